// Round 1
// baseline (8776.674 us; speedup 1.0000x reference)
//
#include <hip/hip_runtime.h>
#include <math.h>

#define N_T 80000
#define N_S 160000
#define D_STATE 400
#define D_EMB 350
#define D_DIST 20
#define HDIM 150
#define GI_DIM 1170

// ---------------------------------------------------------------------------
// Fused 3-layer MLP: out[row] = W3 . relu(W2 . relu(W1^T . A[row] + b1) + b2) + b3
// A: [M][K] f32 row-major. W1: [K][150], W2: [150][150], W3: [150], out: [M]
// Block: 256 threads handles 64 rows. Register tile acc[4][10] per thread.
// Grid: M/64 (M is a multiple of 64 for both call sites).
// ---------------------------------------------------------------------------
template <int K>
__global__ __launch_bounds__(256) void mlp_kernel(
    const float* __restrict__ A,
    const float* __restrict__ W1, const float* __restrict__ b1,
    const float* __restrict__ W2, const float* __restrict__ b2,
    const float* __restrict__ W3, const float* __restrict__ b3,
    float* __restrict__ out)
{
    __shared__ float hb1[64][153];  // h1 (relu'd), padded stride
    __shared__ float hb2[64][153];  // h2 (relu'd)

    const int tid = threadIdx.x;
    const int ty = tid >> 4;        // 0..15 -> rows ty*4 .. ty*4+3
    const int tx = tid & 15;        // 0..15 -> cols tx*10 .. tx*10+9
    const int row0 = blockIdx.x * 64;
    const int colbase = tx * 10;

    // clamped column indices (cols >= 150 compute garbage that is never stored)
    int cidx[10];
#pragma unroll
    for (int c = 0; c < 10; ++c) {
        int col = colbase + c;
        cidx[c] = (col < HDIM) ? col : (HDIM - 1);
    }

    // ---- layer 1: K -> 150 ----
    float acc[4][10];
#pragma unroll
    for (int c = 0; c < 10; ++c) {
        float bv = b1[cidx[c]];
#pragma unroll
        for (int r = 0; r < 4; ++r) acc[r][c] = bv;
    }

    const float* Arow0 = A + (size_t)(row0 + ty * 4 + 0) * K;
    const float* Arow1 = A + (size_t)(row0 + ty * 4 + 1) * K;
    const float* Arow2 = A + (size_t)(row0 + ty * 4 + 2) * K;
    const float* Arow3 = A + (size_t)(row0 + ty * 4 + 3) * K;

#pragma unroll 4
    for (int k = 0; k < K; ++k) {
        const float sv0 = Arow0[k];
        const float sv1 = Arow1[k];
        const float sv2 = Arow2[k];
        const float sv3 = Arow3[k];
        const float* wrow = W1 + (size_t)k * HDIM;
#pragma unroll
        for (int c = 0; c < 10; ++c) {
            const float wv = wrow[cidx[c]];
            acc[0][c] = fmaf(sv0, wv, acc[0][c]);
            acc[1][c] = fmaf(sv1, wv, acc[1][c]);
            acc[2][c] = fmaf(sv2, wv, acc[2][c]);
            acc[3][c] = fmaf(sv3, wv, acc[3][c]);
        }
    }

#pragma unroll
    for (int r = 0; r < 4; ++r) {
#pragma unroll
        for (int c = 0; c < 10; ++c) {
            int col = colbase + c;
            if (col < HDIM) hb1[ty * 4 + r][col] = fmaxf(acc[r][c], 0.0f);
        }
    }
    __syncthreads();

    // ---- layer 2: 150 -> 150 ----
    float acc2[4][10];
#pragma unroll
    for (int c = 0; c < 10; ++c) {
        float bv = b2[cidx[c]];
#pragma unroll
        for (int r = 0; r < 4; ++r) acc2[r][c] = bv;
    }

#pragma unroll 2
    for (int k = 0; k < HDIM; ++k) {
        const float sv0 = hb1[ty * 4 + 0][k];
        const float sv1 = hb1[ty * 4 + 1][k];
        const float sv2 = hb1[ty * 4 + 2][k];
        const float sv3 = hb1[ty * 4 + 3][k];
        const float* wrow = W2 + (size_t)k * HDIM;
#pragma unroll
        for (int c = 0; c < 10; ++c) {
            const float wv = wrow[cidx[c]];
            acc2[0][c] = fmaf(sv0, wv, acc2[0][c]);
            acc2[1][c] = fmaf(sv1, wv, acc2[1][c]);
            acc2[2][c] = fmaf(sv2, wv, acc2[2][c]);
            acc2[3][c] = fmaf(sv3, wv, acc2[3][c]);
        }
    }

#pragma unroll
    for (int r = 0; r < 4; ++r) {
#pragma unroll
        for (int c = 0; c < 10; ++c) {
            int col = colbase + c;
            if (col < HDIM) hb2[ty * 4 + r][col] = fmaxf(acc2[r][c], 0.0f);
        }
    }
    __syncthreads();

    // ---- layer 3: 150 -> 1 ----
    // thread t: row = t/4, part = t%4; butterfly-reduce 4 partials via shfl_xor
    {
        const int row = tid >> 2;
        const int part = tid & 3;
        float ps = 0.0f;
        for (int k = part; k < HDIM; k += 4) ps += hb2[row][k] * W3[k];
        ps += __shfl_xor(ps, 1);
        ps += __shfl_xor(ps, 2);
        if (part == 0) out[row0 + row] = ps + b3[0];
    }
}

// ---------------------------------------------------------------------------
// g_i assembly: one wave per span.
// g_i = [states[i1] (400) | states[i1+w] (400) | attn_embeds (350) | width_emb (20)]
// ---------------------------------------------------------------------------
__global__ __launch_bounds__(256) void gi_kernel(
    const float* __restrict__ states, const float* __restrict__ embeds,
    const int* __restrict__ starts, const int* __restrict__ widths,
    const float* __restrict__ alfa, const float* __restrict__ wtab,
    float* __restrict__ gi)
{
    const int wave = threadIdx.x >> 6;
    const int lane = threadIdx.x & 63;
    const int s = blockIdx.x * 4 + wave;
    if (s >= N_S) return;

    const int i1 = starts[s];
    const int wdt = widths[s];                      // 0 or 1
    int i2 = i1 + wdt; if (i2 > N_T - 1) i2 = N_T - 1;   // span end (used)
    int ie = i1 + 1;  if (ie > N_T - 1) ie = N_T - 1;    // clipped second token

    // span softmax over (at most) 2 tokens, same formula as reference
    const float e0 = expf(alfa[i1]);
    const float e1 = (wdt > 0) ? expf(alfa[ie]) : 0.0f;
    const float inv = 1.0f / (e0 + e1);
    const float w0 = e0 * inv;
    const float w1 = e1 * inv;

    const float* s1 = states + (size_t)i1 * D_STATE;
    const float* s2 = states + (size_t)i2 * D_STATE;
    const float* em1 = embeds + (size_t)i1 * D_EMB;
    const float* em2 = embeds + (size_t)ie * D_EMB;
    const float* wt = wtab + (size_t)(wdt + 1) * D_DIST;  // bin = width+1
    float* g = gi + (size_t)s * GI_DIM;

    for (int j = lane; j < GI_DIM; j += 64) {
        float v;
        if (j < 400) {
            v = s1[j];
        } else if (j < 800) {
            v = s2[j - 400];
        } else if (j < 1150) {
            const int jj = j - 800;
            v = w0 * em1[jj] + w1 * em2[jj];
        } else {
            v = wt[j - 1150];
        }
        g[j] = v;
    }
}

extern "C" void kernel_launch(void* const* d_in, const int* in_sizes, int n_in,
                              void* d_out, int out_size, void* d_ws, size_t ws_size,
                              hipStream_t stream)
{
    const float* states = (const float*)d_in[0];
    const float* embeds = (const float*)d_in[1];
    const int*   starts = (const int*)d_in[2];
    const int*   widths = (const int*)d_in[3];
    const float* aW1 = (const float*)d_in[4];
    const float* ab1 = (const float*)d_in[5];
    const float* aW2 = (const float*)d_in[6];
    const float* ab2 = (const float*)d_in[7];
    const float* aW3 = (const float*)d_in[8];
    const float* ab3 = (const float*)d_in[9];
    const float* wtab = (const float*)d_in[10];
    const float* sW1 = (const float*)d_in[11];
    const float* sb1 = (const float*)d_in[12];
    const float* sW2 = (const float*)d_in[13];
    const float* sb2 = (const float*)d_in[14];
    const float* sW3 = (const float*)d_in[15];
    const float* sb3 = (const float*)d_in[16];

    float* gi = (float*)d_out;                         // [N_S][GI_DIM]
    float* scores = gi + (size_t)N_S * GI_DIM;         // [N_S]
    float* alfa = (float*)d_ws;                        // [N_T] scratch

    // 1) alfa = attention-MLP(states)           (80000 rows, K=400)
    mlp_kernel<D_STATE><<<N_T / 64, 256, 0, stream>>>(
        states, aW1, ab1, aW2, ab2, aW3, ab3, alfa);

    // 2) g_i assembly (one wave per span)
    gi_kernel<<<N_S / 4, 256, 0, stream>>>(
        states, embeds, starts, widths, alfa, wtab, gi);

    // 3) mention scores = mention-MLP(g_i)      (160000 rows, K=1170)
    mlp_kernel<GI_DIM><<<N_S / 64, 256, 0, stream>>>(
        gi, sW1, sb1, sW2, sb2, sW3, sb3, scores);
}

// Round 2
// 735.793 us; speedup vs baseline: 11.9282x; 11.9282x over previous
//
#include <hip/hip_runtime.h>
#include <math.h>

#define N_T 80000
#define N_S 160000
#define D_STATE 400
#define D_EMB 350
#define D_DIST 20
#define HDIM 150
#define GI_DIM 1170

typedef __attribute__((ext_vector_type(8))) short s16x8;
typedef __attribute__((ext_vector_type(4))) float f32x4;

__device__ __forceinline__ unsigned short f2bf(float f) {
    union { float f; unsigned int u; } c; c.f = f;
    unsigned int u = c.u;
    unsigned int r = (u + 0x7fffu + ((u >> 16) & 1u)) >> 16;  // RNE
    return (unsigned short)r;
}
__device__ __forceinline__ float bf2f(unsigned short h) {
    union { unsigned int u; float f; } c; c.u = ((unsigned int)h) << 16;
    return c.f;
}

// ---------------------------------------------------------------------------
// Weight conversion: f32 [K][150] -> bf16 transposed+padded [160][KP]
// ---------------------------------------------------------------------------
__global__ __launch_bounds__(256) void convert_kernel(
    const float* __restrict__ sW1, const float* __restrict__ sW2, const float* __restrict__ sW3,
    const float* __restrict__ aW1, const float* __restrict__ aW2, const float* __restrict__ aW3,
    unsigned short* __restrict__ w1t_m, unsigned short* __restrict__ w2t_m, unsigned short* __restrict__ w3_m,
    unsigned short* __restrict__ w1t_a, unsigned short* __restrict__ w2t_a, unsigned short* __restrict__ w3_a)
{
    int gid = blockIdx.x * 256 + threadIdx.x;
    const int S1 = 160 * 1216, S2 = 160 * 160, S3 = 160, S4 = 160 * 448, S5 = 160 * 160, S6 = 160;
    if (gid < S1) {
        int n = gid / 1216, k = gid % 1216;
        float v = (k < GI_DIM && n < HDIM) ? sW1[k * HDIM + n] : 0.f;
        w1t_m[gid] = f2bf(v); return;
    } gid -= S1;
    if (gid < S2) {
        int n = gid / 160, k = gid % 160;
        float v = (k < HDIM && n < HDIM) ? sW2[k * HDIM + n] : 0.f;
        w2t_m[gid] = f2bf(v); return;
    } gid -= S2;
    if (gid < S3) { w3_m[gid] = (gid < HDIM) ? f2bf(sW3[gid]) : (unsigned short)0; return; } gid -= S3;
    if (gid < S4) {
        int n = gid / 448, k = gid % 448;
        float v = (k < D_STATE && n < HDIM) ? aW1[k * HDIM + n] : 0.f;
        w1t_a[gid] = f2bf(v); return;
    } gid -= S4;
    if (gid < S5) {
        int n = gid / 160, k = gid % 160;
        float v = (k < HDIM && n < HDIM) ? aW2[k * HDIM + n] : 0.f;
        w2t_a[gid] = f2bf(v); return;
    } gid -= S5;
    if (gid < S6) { w3_a[gid] = (gid < HDIM) ? f2bf(aW3[gid]) : (unsigned short)0; }
}

// ---------------------------------------------------------------------------
// Fused 3-layer MLP via bf16 MFMA (f32 accumulate).
//   out[row] = W3 . relu(W2 . relu(W1^T A[row] + b1) + b2) + b3
// A: [M][K] f32. w1t: [160][NT*64] bf16 (transposed, zero-padded).
// w2t: [160][160] bf16 (transposed, padded). w3: [160] bf16 (padded).
// Block: 256 thr / 4 waves; M-tile 128 (32 rows/wave); N padded to 160.
// ---------------------------------------------------------------------------
template <int K, int NT>
__global__ __launch_bounds__(256) void mlp_mfma(
    const float* __restrict__ A,
    const unsigned short* __restrict__ w1t, const float* __restrict__ b1,
    const unsigned short* __restrict__ w2t, const float* __restrict__ b2,
    const unsigned short* __restrict__ w3, const float* __restrict__ b3,
    float* __restrict__ out)
{
    constexpr int KP = NT * 64;
    // K-loop phase: sA [128][64] bf16 swizzled @0 (16384B), sB [160][64] bf16 swizzled @16384 (20480B)
    // layer-2 phase: sH [128 rows][336B] bf16 @0 (43008B)
    __shared__ __align__(16) char smem[43008];
    const int SB_OFF = 16384;

    const int tid = threadIdx.x;
    const int w = tid >> 6;
    const int l = tid & 63;
    const int l15 = l & 15;
    const int lg = l >> 4;
    const int row0 = blockIdx.x * 128;

    // A-staging mapping: 2 threads per row, 32 cols each
    const int arow = tid >> 1;
    const int acb = (tid & 1) * 32;

    f32x4 acc[2][10];
#pragma unroll
    for (int rf = 0; rf < 2; ++rf)
#pragma unroll
        for (int nf = 0; nf < 10; ++nf) acc[rf][nf] = (f32x4){0.f, 0.f, 0.f, 0.f};

    const int arow_base = w * 32 + l15;
    const int asw = (arow_base & 7) << 4;

    for (int t = 0; t < NT; ++t) {
        const int k0 = t * 64;
        __syncthreads();

        // ---- stage A tile (f32 -> bf16, swizzled) ----
        unsigned short tmp[32];
        if (k0 + 64 <= K) {
            const float* src = A + (size_t)(row0 + arow) * K + k0 + acb;
#pragma unroll
            for (int i = 0; i < 16; ++i) {
                float2 v = ((const float2*)src)[i];
                tmp[2 * i] = f2bf(v.x);
                tmp[2 * i + 1] = f2bf(v.y);
            }
        } else {
            const float* arp = A + (size_t)(row0 + arow) * K;
#pragma unroll
            for (int i = 0; i < 32; ++i) {
                int col = k0 + acb + i;
                tmp[i] = (col < K) ? f2bf(arp[col]) : (unsigned short)0;
            }
        }
        {
            const int sw = (arow & 7) << 4;
#pragma unroll
            for (int i = 0; i < 4; ++i) {
                s16x8 pv;
#pragma unroll
                for (int j = 0; j < 8; ++j) pv[j] = (short)tmp[i * 8 + j];
                int inrow = acb * 2 + i * 16;
                *(s16x8*)(smem + arow * 128 + (inrow ^ sw)) = pv;
            }
        }

        // ---- stage B tile (bf16 copy, swizzled): 160 rows x 64 k ----
#pragma unroll
        for (int i = 0; i < 5; ++i) {
            int idx = i * 256 + tid;
            int n = idx >> 3, s2 = idx & 7;
            s16x8 v = *(const s16x8*)(w1t + (size_t)n * KP + k0 + s2 * 8);
            int inrow = s2 * 16;
            *(s16x8*)(smem + SB_OFF + n * 128 + (inrow ^ ((n & 7) << 4))) = v;
        }

        __syncthreads();

        // ---- MFMA: 2 kc x 2 rf x 10 nf ----
#pragma unroll
        for (int kc = 0; kc < 2; ++kc) {
            const int inrowA = kc * 64 + lg * 16;
            s16x8 a0 = *(const s16x8*)(smem + arow_base * 128 + (inrowA ^ asw));
            s16x8 a1 = *(const s16x8*)(smem + arow_base * 128 + 2048 + (inrowA ^ asw));
#pragma unroll
            for (int nf = 0; nf < 10; ++nf) {
                const int n = nf * 16 + l15;
                s16x8 b = *(const s16x8*)(smem + SB_OFF + n * 128 + (inrowA ^ ((n & 7) << 4)));
                acc[0][nf] = __builtin_amdgcn_mfma_f32_16x16x32_bf16(a0, b, acc[0][nf], 0, 0, 0);
                acc[1][nf] = __builtin_amdgcn_mfma_f32_16x16x32_bf16(a1, b, acc[1][nf], 0, 0, 0);
            }
        }
    }

    __syncthreads();  // done with sA/sB, reuse as sH

    // ---- h1 = relu(acc + b1) -> sH bf16 [128][336B rows] ----
    {
        float b1c[10];
#pragma unroll
        for (int nf = 0; nf < 10; ++nf) {
            int col = nf * 16 + l15;
            b1c[nf] = (col < HDIM) ? b1[col] : 0.f;
        }
#pragma unroll
        for (int rf = 0; rf < 2; ++rf)
#pragma unroll
            for (int nf = 0; nf < 10; ++nf)
#pragma unroll
                for (int r = 0; r < 4; ++r) {
                    int row = w * 32 + rf * 16 + lg * 4 + r;
                    int col = nf * 16 + l15;
                    float h = fmaxf(acc[rf][nf][r] + b1c[nf], 0.f);
                    *(unsigned short*)(smem + row * 336 + col * 2) = f2bf(h);
                }
    }
    __syncthreads();

    // ---- layer 2: h1[128][160] x W2T -> acc2, B-frags straight from L2 ----
    f32x4 acc2[2][10];
#pragma unroll
    for (int rf = 0; rf < 2; ++rf)
#pragma unroll
        for (int nf = 0; nf < 10; ++nf) acc2[rf][nf] = (f32x4){0.f, 0.f, 0.f, 0.f};

#pragma unroll
    for (int kc = 0; kc < 5; ++kc) {
        s16x8 a0 = *(const s16x8*)(smem + (w * 32 + l15) * 336 + kc * 64 + lg * 16);
        s16x8 a1 = *(const s16x8*)(smem + (w * 32 + 16 + l15) * 336 + kc * 64 + lg * 16);
#pragma unroll
        for (int nf = 0; nf < 10; ++nf) {
            const int n = nf * 16 + l15;
            s16x8 b = *(const s16x8*)(w2t + n * 160 + kc * 32 + lg * 8);
            acc2[0][nf] = __builtin_amdgcn_mfma_f32_16x16x32_bf16(a0, b, acc2[0][nf], 0, 0, 0);
            acc2[1][nf] = __builtin_amdgcn_mfma_f32_16x16x32_bf16(a1, b, acc2[1][nf], 0, 0, 0);
        }
    }

    // ---- layer 3: score = relu(acc2 + b2) . W3 + b3, reduce over 16 lanes ----
    {
        float b2c[10], w3c[10];
#pragma unroll
        for (int nf = 0; nf < 10; ++nf) {
            int col = nf * 16 + l15;
            b2c[nf] = (col < HDIM) ? b2[col] : 0.f;
            w3c[nf] = bf2f(w3[col]);  // zero-padded beyond 150
        }
#pragma unroll
        for (int rf = 0; rf < 2; ++rf)
#pragma unroll
            for (int r = 0; r < 4; ++r) {
                float ps = 0.f;
#pragma unroll
                for (int nf = 0; nf < 10; ++nf)
                    ps += fmaxf(acc2[rf][nf][r] + b2c[nf], 0.f) * w3c[nf];
                ps += __shfl_xor(ps, 1);
                ps += __shfl_xor(ps, 2);
                ps += __shfl_xor(ps, 4);
                ps += __shfl_xor(ps, 8);
                if (l15 == 0)
                    out[row0 + w * 32 + rf * 16 + lg * 4 + r] = ps + b3[0];
            }
    }
}

// ---------------------------------------------------------------------------
// g_i assembly: one wave per span (unchanged from round 1, ref-verified).
// ---------------------------------------------------------------------------
__global__ __launch_bounds__(256) void gi_kernel(
    const float* __restrict__ states, const float* __restrict__ embeds,
    const int* __restrict__ starts, const int* __restrict__ widths,
    const float* __restrict__ alfa, const float* __restrict__ wtab,
    float* __restrict__ gi)
{
    const int wave = threadIdx.x >> 6;
    const int lane = threadIdx.x & 63;
    const int s = blockIdx.x * 4 + wave;
    if (s >= N_S) return;

    const int i1 = starts[s];
    const int wdt = widths[s];
    int i2 = i1 + wdt; if (i2 > N_T - 1) i2 = N_T - 1;
    int ie = i1 + 1;  if (ie > N_T - 1) ie = N_T - 1;

    const float e0 = expf(alfa[i1]);
    const float e1 = (wdt > 0) ? expf(alfa[ie]) : 0.0f;
    const float inv = 1.0f / (e0 + e1);
    const float w0 = e0 * inv;
    const float w1 = e1 * inv;

    const float* s1 = states + (size_t)i1 * D_STATE;
    const float* s2 = states + (size_t)i2 * D_STATE;
    const float* em1 = embeds + (size_t)i1 * D_EMB;
    const float* em2 = embeds + (size_t)ie * D_EMB;
    const float* wt = wtab + (size_t)(wdt + 1) * D_DIST;
    float* g = gi + (size_t)s * GI_DIM;

    for (int j = lane; j < GI_DIM; j += 64) {
        float v;
        if (j < 400) v = s1[j];
        else if (j < 800) v = s2[j - 400];
        else if (j < 1150) { const int jj = j - 800; v = w0 * em1[jj] + w1 * em2[jj]; }
        else v = wt[j - 1150];
        g[j] = v;
    }
}

extern "C" void kernel_launch(void* const* d_in, const int* in_sizes, int n_in,
                              void* d_out, int out_size, void* d_ws, size_t ws_size,
                              hipStream_t stream)
{
    const float* states = (const float*)d_in[0];
    const float* embeds = (const float*)d_in[1];
    const int*   starts = (const int*)d_in[2];
    const int*   widths = (const int*)d_in[3];
    const float* aW1 = (const float*)d_in[4];
    const float* ab1 = (const float*)d_in[5];
    const float* aW2 = (const float*)d_in[6];
    const float* ab2 = (const float*)d_in[7];
    const float* aW3 = (const float*)d_in[8];
    const float* ab3 = (const float*)d_in[9];
    const float* wtab = (const float*)d_in[10];
    const float* sW1 = (const float*)d_in[11];
    const float* sb1 = (const float*)d_in[12];
    const float* sW2 = (const float*)d_in[13];
    const float* sb2 = (const float*)d_in[14];
    const float* sW3 = (const float*)d_in[15];
    const float* sb3 = (const float*)d_in[16];

    float* gi = (float*)d_out;
    float* scores = gi + (size_t)N_S * GI_DIM;

    // workspace layout (bytes, 16-aligned)
    char* ws = (char*)d_ws;
    float* alfa = (float*)ws;                                   // 320000 B
    unsigned short* w1t_m = (unsigned short*)(ws + 320512);     // 160*1216*2 = 389120
    unsigned short* w2t_m = (unsigned short*)(ws + 709632);     // 51200
    unsigned short* w3_m  = (unsigned short*)(ws + 760832);     // 320
    unsigned short* w1t_a = (unsigned short*)(ws + 761344);     // 160*448*2 = 143360
    unsigned short* w2t_a = (unsigned short*)(ws + 904704);     // 51200
    unsigned short* w3_a  = (unsigned short*)(ws + 955904);     // 320

    // 0) convert/transpose/pad weights to bf16
    convert_kernel<<<1242, 256, 0, stream>>>(sW1, sW2, sW3, aW1, aW2, aW3,
                                             w1t_m, w2t_m, w3_m, w1t_a, w2t_a, w3_a);

    // 1) alfa = attention-MLP(states): M=80000, K=400 (7 K-tiles)
    mlp_mfma<D_STATE, 7><<<N_T / 128, 256, 0, stream>>>(
        states, w1t_a, ab1, w2t_a, ab2, w3_a, ab3, alfa);

    // 2) g_i assembly
    gi_kernel<<<N_S / 4, 256, 0, stream>>>(
        states, embeds, starts, widths, alfa, wtab, gi);

    // 3) mention scores: M=160000, K=1170 (19 K-tiles)
    mlp_mfma<GI_DIM, 19><<<N_S / 128, 256, 0, stream>>>(
        gi, w1t_m, sb1, w2t_m, sb2, w3_m, sb3, scores);
}

// Round 3
// 734.645 us; speedup vs baseline: 11.9468x; 1.0016x over previous
//
#include <hip/hip_runtime.h>
#include <math.h>

#define N_T 80000
#define N_S 160000
#define D_STATE 400
#define D_EMB 350
#define D_DIST 20
#define HDIM 150
#define GI_DIM 1170

typedef __attribute__((ext_vector_type(8))) short s16x8;
typedef __attribute__((ext_vector_type(4))) float f32x4;

__device__ __forceinline__ unsigned short f2bf(float f) {
    union { float f; unsigned int u; } c; c.f = f;
    unsigned int u = c.u;
    unsigned int r = (u + 0x7fffu + ((u >> 16) & 1u)) >> 16;  // RNE
    return (unsigned short)r;
}
__device__ __forceinline__ float bf2f(unsigned short h) {
    union { unsigned int u; float f; } c; c.u = ((unsigned int)h) << 16;
    return c.f;
}

// ---------------------------------------------------------------------------
// Weight conversion: f32 [K][150] -> bf16 transposed+padded [160][KP]
// ---------------------------------------------------------------------------
__global__ __launch_bounds__(256) void convert_kernel(
    const float* __restrict__ sW1, const float* __restrict__ sW2, const float* __restrict__ sW3,
    const float* __restrict__ aW1, const float* __restrict__ aW2, const float* __restrict__ aW3,
    unsigned short* __restrict__ w1t_m, unsigned short* __restrict__ w2t_m, unsigned short* __restrict__ w3_m,
    unsigned short* __restrict__ w1t_a, unsigned short* __restrict__ w2t_a, unsigned short* __restrict__ w3_a)
{
    int gid = blockIdx.x * 256 + threadIdx.x;
    const int S1 = 160 * 1216, S2 = 160 * 160, S3 = 160, S4 = 160 * 448, S5 = 160 * 160, S6 = 160;
    if (gid < S1) {
        int n = gid / 1216, k = gid % 1216;
        float v = (k < GI_DIM && n < HDIM) ? sW1[k * HDIM + n] : 0.f;
        w1t_m[gid] = f2bf(v); return;
    } gid -= S1;
    if (gid < S2) {
        int n = gid / 160, k = gid % 160;
        float v = (k < HDIM && n < HDIM) ? sW2[k * HDIM + n] : 0.f;
        w2t_m[gid] = f2bf(v); return;
    } gid -= S2;
    if (gid < S3) { w3_m[gid] = (gid < HDIM) ? f2bf(sW3[gid]) : (unsigned short)0; return; } gid -= S3;
    if (gid < S4) {
        int n = gid / 448, k = gid % 448;
        float v = (k < D_STATE && n < HDIM) ? aW1[k * HDIM + n] : 0.f;
        w1t_a[gid] = f2bf(v); return;
    } gid -= S4;
    if (gid < S5) {
        int n = gid / 160, k = gid % 160;
        float v = (k < HDIM && n < HDIM) ? aW2[k * HDIM + n] : 0.f;
        w2t_a[gid] = f2bf(v); return;
    } gid -= S5;
    if (gid < S6) { w3_a[gid] = (gid < HDIM) ? f2bf(aW3[gid]) : (unsigned short)0; }
}

// ---------------------------------------------------------------------------
// Attention MLP (unchanged from round 2): A [M][K] f32 -> out [M]
// ---------------------------------------------------------------------------
template <int K, int NT>
__global__ __launch_bounds__(256) void mlp_mfma(
    const float* __restrict__ A,
    const unsigned short* __restrict__ w1t, const float* __restrict__ b1,
    const unsigned short* __restrict__ w2t, const float* __restrict__ b2,
    const unsigned short* __restrict__ w3, const float* __restrict__ b3,
    float* __restrict__ out)
{
    constexpr int KP = NT * 64;
    __shared__ __align__(16) char smem[43008];
    const int SB_OFF = 16384;

    const int tid = threadIdx.x;
    const int w = tid >> 6;
    const int l = tid & 63;
    const int l15 = l & 15;
    const int lg = l >> 4;
    const int row0 = blockIdx.x * 128;

    const int arow = tid >> 1;
    const int acb = (tid & 1) * 32;

    f32x4 acc[2][10];
#pragma unroll
    for (int rf = 0; rf < 2; ++rf)
#pragma unroll
        for (int nf = 0; nf < 10; ++nf) acc[rf][nf] = (f32x4){0.f, 0.f, 0.f, 0.f};

    const int arow_base = w * 32 + l15;
    const int asw = (arow_base & 7) << 4;

    for (int t = 0; t < NT; ++t) {
        const int k0 = t * 64;
        __syncthreads();

        unsigned short tmp[32];
        if (k0 + 64 <= K) {
            const float* src = A + (size_t)(row0 + arow) * K + k0 + acb;
#pragma unroll
            for (int i = 0; i < 16; ++i) {
                float2 v = ((const float2*)src)[i];
                tmp[2 * i] = f2bf(v.x);
                tmp[2 * i + 1] = f2bf(v.y);
            }
        } else {
            const float* arp = A + (size_t)(row0 + arow) * K;
#pragma unroll
            for (int i = 0; i < 32; ++i) {
                int col = k0 + acb + i;
                tmp[i] = (col < K) ? f2bf(arp[col]) : (unsigned short)0;
            }
        }
        {
            const int sw = (arow & 7) << 4;
#pragma unroll
            for (int i = 0; i < 4; ++i) {
                s16x8 pv;
#pragma unroll
                for (int j = 0; j < 8; ++j) pv[j] = (short)tmp[i * 8 + j];
                int inrow = acb * 2 + i * 16;
                *(s16x8*)(smem + arow * 128 + (inrow ^ sw)) = pv;
            }
        }

#pragma unroll
        for (int i = 0; i < 5; ++i) {
            int idx = i * 256 + tid;
            int n = idx >> 3, s2 = idx & 7;
            s16x8 v = *(const s16x8*)(w1t + (size_t)n * KP + k0 + s2 * 8);
            int inrow = s2 * 16;
            *(s16x8*)(smem + SB_OFF + n * 128 + (inrow ^ ((n & 7) << 4))) = v;
        }

        __syncthreads();

#pragma unroll
        for (int kc = 0; kc < 2; ++kc) {
            const int inrowA = kc * 64 + lg * 16;
            s16x8 a0 = *(const s16x8*)(smem + arow_base * 128 + (inrowA ^ asw));
            s16x8 a1 = *(const s16x8*)(smem + arow_base * 128 + 2048 + (inrowA ^ asw));
#pragma unroll
            for (int nf = 0; nf < 10; ++nf) {
                const int n = nf * 16 + l15;
                s16x8 b = *(const s16x8*)(smem + SB_OFF + n * 128 + (inrowA ^ ((n & 7) << 4)));
                acc[0][nf] = __builtin_amdgcn_mfma_f32_16x16x32_bf16(a0, b, acc[0][nf], 0, 0, 0);
                acc[1][nf] = __builtin_amdgcn_mfma_f32_16x16x32_bf16(a1, b, acc[1][nf], 0, 0, 0);
            }
        }
    }

    __syncthreads();

    {
        float b1c[10];
#pragma unroll
        for (int nf = 0; nf < 10; ++nf) {
            int col = nf * 16 + l15;
            b1c[nf] = (col < HDIM) ? b1[col] : 0.f;
        }
#pragma unroll
        for (int rf = 0; rf < 2; ++rf)
#pragma unroll
            for (int nf = 0; nf < 10; ++nf)
#pragma unroll
                for (int r = 0; r < 4; ++r) {
                    int row = w * 32 + rf * 16 + lg * 4 + r;
                    int col = nf * 16 + l15;
                    float h = fmaxf(acc[rf][nf][r] + b1c[nf], 0.f);
                    *(unsigned short*)(smem + row * 336 + col * 2) = f2bf(h);
                }
    }
    __syncthreads();

    f32x4 acc2[2][10];
#pragma unroll
    for (int rf = 0; rf < 2; ++rf)
#pragma unroll
        for (int nf = 0; nf < 10; ++nf) acc2[rf][nf] = (f32x4){0.f, 0.f, 0.f, 0.f};

#pragma unroll
    for (int kc = 0; kc < 5; ++kc) {
        s16x8 a0 = *(const s16x8*)(smem + (w * 32 + l15) * 336 + kc * 64 + lg * 16);
        s16x8 a1 = *(const s16x8*)(smem + (w * 32 + 16 + l15) * 336 + kc * 64 + lg * 16);
#pragma unroll
        for (int nf = 0; nf < 10; ++nf) {
            const int n = nf * 16 + l15;
            s16x8 b = *(const s16x8*)(w2t + n * 160 + kc * 32 + lg * 8);
            acc2[0][nf] = __builtin_amdgcn_mfma_f32_16x16x32_bf16(a0, b, acc2[0][nf], 0, 0, 0);
            acc2[1][nf] = __builtin_amdgcn_mfma_f32_16x16x32_bf16(a1, b, acc2[1][nf], 0, 0, 0);
        }
    }

    {
        float b2c[10], w3c[10];
#pragma unroll
        for (int nf = 0; nf < 10; ++nf) {
            int col = nf * 16 + l15;
            b2c[nf] = (col < HDIM) ? b2[col] : 0.f;
            w3c[nf] = bf2f(w3[col]);
        }
#pragma unroll
        for (int rf = 0; rf < 2; ++rf)
#pragma unroll
            for (int r = 0; r < 4; ++r) {
                float ps = 0.f;
#pragma unroll
                for (int nf = 0; nf < 10; ++nf)
                    ps += fmaxf(acc2[rf][nf][r] + b2c[nf], 0.f) * w3c[nf];
                ps += __shfl_xor(ps, 1);
                ps += __shfl_xor(ps, 2);
                ps += __shfl_xor(ps, 4);
                ps += __shfl_xor(ps, 8);
                if (l15 == 0)
                    out[row0 + w * 32 + rf * 16 + lg * 4 + r] = ps + b3[0];
            }
    }
}

// ---------------------------------------------------------------------------
// Fused mention kernel: builds g_i on the fly (writes f32 g_i to d_out AND
// bf16 A-tiles to LDS), then 3-layer MFMA MLP. 128 spans per block.
// ---------------------------------------------------------------------------
__global__ __launch_bounds__(256) void mention_fused(
    const float* __restrict__ states, const float* __restrict__ embeds,
    const int* __restrict__ starts, const int* __restrict__ widths,
    const float* __restrict__ alfa, const float* __restrict__ wtab,
    const unsigned short* __restrict__ w1t, const float* __restrict__ b1,
    const unsigned short* __restrict__ w2t, const float* __restrict__ b2,
    const unsigned short* __restrict__ w3, const float* __restrict__ b3,
    float* __restrict__ gi, float* __restrict__ out)
{
    constexpr int NT = 19;
    constexpr int KP = NT * 64;  // 1216
    __shared__ __align__(16) char smem[43008];
    const int SB_OFF = 16384;

    const int tid = threadIdx.x;
    const int w = tid >> 6;
    const int l = tid & 63;
    const int l15 = l & 15;
    const int lg = l >> 4;
    const int row0 = blockIdx.x * 128;

    const int arow = tid >> 1;          // span slot 0..127
    const int acb = (tid & 1) * 32;     // col sub-window

    // ---- per-thread span prologue (g_i source pointers + softmax weights) ----
    const int srow = row0 + arow;
    const int i1 = starts[srow];
    const int wdt = widths[srow];
    int i2 = i1 + wdt; if (i2 > N_T - 1) i2 = N_T - 1;
    int ie = i1 + 1;  if (ie > N_T - 1) ie = N_T - 1;
    const float e0 = expf(alfa[i1]);
    const float e1 = (wdt > 0) ? expf(alfa[ie]) : 0.0f;
    const float inv = 1.0f / (e0 + e1);
    const float w0 = e0 * inv;
    const float w1v = e1 * inv;
    const float* __restrict__ sp1 = states + (size_t)i1 * D_STATE;
    const float* __restrict__ sp2 = states + (size_t)i2 * D_STATE;
    const float* __restrict__ em1 = embeds + (size_t)i1 * D_EMB;
    const float* __restrict__ em2 = embeds + (size_t)ie * D_EMB;
    const float* __restrict__ wt = wtab + (size_t)(wdt + 1) * D_DIST;
    float* __restrict__ grow = gi + (size_t)srow * GI_DIM;

    f32x4 acc[2][10];
#pragma unroll
    for (int rf = 0; rf < 2; ++rf)
#pragma unroll
        for (int nf = 0; nf < 10; ++nf) acc[rf][nf] = (f32x4){0.f, 0.f, 0.f, 0.f};

    const int arow_base = w * 32 + l15;
    const int asw = (arow_base & 7) << 4;
    const int sw = (arow & 7) << 4;

    for (int t = 0; t < NT; ++t) {
        const int k0 = t * 64;
        __syncthreads();

        // ---- build g_i window [k0+acb, k0+acb+32): f32 -> d_out, bf16 -> LDS ----
#pragma unroll
        for (int i = 0; i < 4; ++i) {
            const int j0 = k0 + acb + i * 8;
            float v[8];
            if (j0 + 8 <= 400) {
                float4 q0 = *(const float4*)(sp1 + j0);
                float4 q1 = *(const float4*)(sp1 + j0 + 4);
                v[0] = q0.x; v[1] = q0.y; v[2] = q0.z; v[3] = q0.w;
                v[4] = q1.x; v[5] = q1.y; v[6] = q1.z; v[7] = q1.w;
            } else if (j0 >= 400 && j0 + 8 <= 800) {
                const int jj = j0 - 400;
                float4 q0 = *(const float4*)(sp2 + jj);
                float4 q1 = *(const float4*)(sp2 + jj + 4);
                v[0] = q0.x; v[1] = q0.y; v[2] = q0.z; v[3] = q0.w;
                v[4] = q1.x; v[5] = q1.y; v[6] = q1.z; v[7] = q1.w;
            } else if (j0 >= 800 && j0 + 8 <= 1150) {
                const int jj = j0 - 800;
#pragma unroll
                for (int q = 0; q < 4; ++q) {
                    float2 ea = *(const float2*)(em1 + jj + 2 * q);
                    float2 eb = *(const float2*)(em2 + jj + 2 * q);
                    v[2 * q]     = w0 * ea.x + w1v * eb.x;
                    v[2 * q + 1] = w0 * ea.y + w1v * eb.y;
                }
            } else if (j0 >= 1170) {
#pragma unroll
                for (int q = 0; q < 8; ++q) v[q] = 0.f;
            } else {
#pragma unroll
                for (int q = 0; q < 8; ++q) {
                    const int j = j0 + q;
                    float val;
                    if (j < 400) val = sp1[j];
                    else if (j < 800) val = sp2[j - 400];
                    else if (j < 1150) val = w0 * em1[j - 800] + w1v * em2[j - 800];
                    else if (j < GI_DIM) val = wt[j - 1150];
                    else val = 0.f;
                    v[q] = val;
                }
            }

            // write f32 g_i (8-aligned float2 stores; rows are 8-byte aligned)
            if (j0 + 8 <= GI_DIM) {
#pragma unroll
                for (int q = 0; q < 4; ++q) {
                    float2 p; p.x = v[2 * q]; p.y = v[2 * q + 1];
                    *(float2*)(grow + j0 + 2 * q) = p;
                }
            } else if (j0 < GI_DIM) {
#pragma unroll
                for (int q = 0; q < 8; ++q)
                    if (j0 + q < GI_DIM) grow[j0 + q] = v[q];
            }

            // pack bf16 -> swizzled LDS A-tile
            s16x8 pv;
#pragma unroll
            for (int q = 0; q < 8; ++q) pv[q] = (short)f2bf(v[q]);
            const int inrow = acb * 2 + i * 16;
            *(s16x8*)(smem + arow * 128 + (inrow ^ sw)) = pv;
        }

        // ---- stage B tile ----
#pragma unroll
        for (int i = 0; i < 5; ++i) {
            int idx = i * 256 + tid;
            int n = idx >> 3, s2 = idx & 7;
            s16x8 v = *(const s16x8*)(w1t + (size_t)n * KP + k0 + s2 * 8);
            int inrow = s2 * 16;
            *(s16x8*)(smem + SB_OFF + n * 128 + (inrow ^ ((n & 7) << 4))) = v;
        }

        __syncthreads();

        // ---- MFMA ----
#pragma unroll
        for (int kc = 0; kc < 2; ++kc) {
            const int inrowA = kc * 64 + lg * 16;
            s16x8 a0 = *(const s16x8*)(smem + arow_base * 128 + (inrowA ^ asw));
            s16x8 a1 = *(const s16x8*)(smem + arow_base * 128 + 2048 + (inrowA ^ asw));
#pragma unroll
            for (int nf = 0; nf < 10; ++nf) {
                const int n = nf * 16 + l15;
                s16x8 b = *(const s16x8*)(smem + SB_OFF + n * 128 + (inrowA ^ ((n & 7) << 4)));
                acc[0][nf] = __builtin_amdgcn_mfma_f32_16x16x32_bf16(a0, b, acc[0][nf], 0, 0, 0);
                acc[1][nf] = __builtin_amdgcn_mfma_f32_16x16x32_bf16(a1, b, acc[1][nf], 0, 0, 0);
            }
        }
    }

    __syncthreads();

    // ---- h1 = relu(acc + b1) -> sH bf16 [128][336B] ----
    {
        float b1c[10];
#pragma unroll
        for (int nf = 0; nf < 10; ++nf) {
            int col = nf * 16 + l15;
            b1c[nf] = (col < HDIM) ? b1[col] : 0.f;
        }
#pragma unroll
        for (int rf = 0; rf < 2; ++rf)
#pragma unroll
            for (int nf = 0; nf < 10; ++nf)
#pragma unroll
                for (int r = 0; r < 4; ++r) {
                    int row = w * 32 + rf * 16 + lg * 4 + r;
                    int col = nf * 16 + l15;
                    float h = fmaxf(acc[rf][nf][r] + b1c[nf], 0.f);
                    *(unsigned short*)(smem + row * 336 + col * 2) = f2bf(h);
                }
    }
    __syncthreads();

    // ---- layer 2 ----
    f32x4 acc2[2][10];
#pragma unroll
    for (int rf = 0; rf < 2; ++rf)
#pragma unroll
        for (int nf = 0; nf < 10; ++nf) acc2[rf][nf] = (f32x4){0.f, 0.f, 0.f, 0.f};

#pragma unroll
    for (int kc = 0; kc < 5; ++kc) {
        s16x8 a0 = *(const s16x8*)(smem + (w * 32 + l15) * 336 + kc * 64 + lg * 16);
        s16x8 a1 = *(const s16x8*)(smem + (w * 32 + 16 + l15) * 336 + kc * 64 + lg * 16);
#pragma unroll
        for (int nf = 0; nf < 10; ++nf) {
            const int n = nf * 16 + l15;
            s16x8 b = *(const s16x8*)(w2t + n * 160 + kc * 32 + lg * 8);
            acc2[0][nf] = __builtin_amdgcn_mfma_f32_16x16x32_bf16(a0, b, acc2[0][nf], 0, 0, 0);
            acc2[1][nf] = __builtin_amdgcn_mfma_f32_16x16x32_bf16(a1, b, acc2[1][nf], 0, 0, 0);
        }
    }

    // ---- layer 3 ----
    {
        float b2c[10], w3c[10];
#pragma unroll
        for (int nf = 0; nf < 10; ++nf) {
            int col = nf * 16 + l15;
            b2c[nf] = (col < HDIM) ? b2[col] : 0.f;
            w3c[nf] = bf2f(w3[col]);
        }
#pragma unroll
        for (int rf = 0; rf < 2; ++rf)
#pragma unroll
            for (int r = 0; r < 4; ++r) {
                float ps = 0.f;
#pragma unroll
                for (int nf = 0; nf < 10; ++nf)
                    ps += fmaxf(acc2[rf][nf][r] + b2c[nf], 0.f) * w3c[nf];
                ps += __shfl_xor(ps, 1);
                ps += __shfl_xor(ps, 2);
                ps += __shfl_xor(ps, 4);
                ps += __shfl_xor(ps, 8);
                if (l15 == 0)
                    out[row0 + w * 32 + rf * 16 + lg * 4 + r] = ps + b3[0];
            }
    }
}

extern "C" void kernel_launch(void* const* d_in, const int* in_sizes, int n_in,
                              void* d_out, int out_size, void* d_ws, size_t ws_size,
                              hipStream_t stream)
{
    const float* states = (const float*)d_in[0];
    const float* embeds = (const float*)d_in[1];
    const int*   starts = (const int*)d_in[2];
    const int*   widths = (const int*)d_in[3];
    const float* aW1 = (const float*)d_in[4];
    const float* ab1 = (const float*)d_in[5];
    const float* aW2 = (const float*)d_in[6];
    const float* ab2 = (const float*)d_in[7];
    const float* aW3 = (const float*)d_in[8];
    const float* ab3 = (const float*)d_in[9];
    const float* wtab = (const float*)d_in[10];
    const float* sW1 = (const float*)d_in[11];
    const float* sb1 = (const float*)d_in[12];
    const float* sW2 = (const float*)d_in[13];
    const float* sb2 = (const float*)d_in[14];
    const float* sW3 = (const float*)d_in[15];
    const float* sb3 = (const float*)d_in[16];

    float* gi = (float*)d_out;
    float* scores = gi + (size_t)N_S * GI_DIM;

    char* ws = (char*)d_ws;
    float* alfa = (float*)ws;                                   // 320000 B
    unsigned short* w1t_m = (unsigned short*)(ws + 320512);
    unsigned short* w2t_m = (unsigned short*)(ws + 709632);
    unsigned short* w3_m  = (unsigned short*)(ws + 760832);
    unsigned short* w1t_a = (unsigned short*)(ws + 761344);
    unsigned short* w2t_a = (unsigned short*)(ws + 904704);
    unsigned short* w3_a  = (unsigned short*)(ws + 955904);

    // 0) convert/transpose/pad weights to bf16
    convert_kernel<<<1242, 256, 0, stream>>>(sW1, sW2, sW3, aW1, aW2, aW3,
                                             w1t_m, w2t_m, w3_m, w1t_a, w2t_a, w3_a);

    // 1) alfa = attention-MLP(states)
    mlp_mfma<D_STATE, 7><<<N_T / 128, 256, 0, stream>>>(
        states, w1t_a, ab1, w2t_a, ab2, w3_a, ab3, alfa);

    // 2+3) fused: g_i assembly + mention MLP
    mention_fused<<<N_S / 128, 256, 0, stream>>>(
        states, embeds, starts, widths, alfa, wtab,
        w1t_m, sb1, w2t_m, sb2, w3_m, sb3, gi, scores);
}

// Round 4
// 725.895 us; speedup vs baseline: 12.0908x; 1.0121x over previous
//
#include <hip/hip_runtime.h>
#include <math.h>

#define N_T 80000
#define N_S 160000
#define D_STATE 400
#define D_EMB 350
#define D_DIST 20
#define HDIM 150
#define GI_DIM 1170

typedef __attribute__((ext_vector_type(8))) short s16x8;
typedef __attribute__((ext_vector_type(4))) float f32x4;

__device__ __forceinline__ unsigned short f2bf(float f) {
    union { float f; unsigned int u; } c; c.f = f;
    unsigned int u = c.u;
    unsigned int r = (u + 0x7fffu + ((u >> 16) & 1u)) >> 16;  // RNE
    return (unsigned short)r;
}
__device__ __forceinline__ float bf2f(unsigned short h) {
    union { unsigned int u; float f; } c; c.u = ((unsigned int)h) << 16;
    return c.f;
}

// ---------------------------------------------------------------------------
// Weight conversion: f32 [K][150] -> bf16 transposed+padded [160][KP]
// ---------------------------------------------------------------------------
__global__ __launch_bounds__(256) void convert_kernel(
    const float* __restrict__ sW1, const float* __restrict__ sW2, const float* __restrict__ sW3,
    const float* __restrict__ aW1, const float* __restrict__ aW2, const float* __restrict__ aW3,
    unsigned short* __restrict__ w1t_m, unsigned short* __restrict__ w2t_m, unsigned short* __restrict__ w3_m,
    unsigned short* __restrict__ w1t_a, unsigned short* __restrict__ w2t_a, unsigned short* __restrict__ w3_a)
{
    int gid = blockIdx.x * 256 + threadIdx.x;
    const int S1 = 160 * 1216, S2 = 160 * 160, S3 = 160, S4 = 160 * 448, S5 = 160 * 160, S6 = 160;
    if (gid < S1) {
        int n = gid / 1216, k = gid % 1216;
        float v = (k < GI_DIM && n < HDIM) ? sW1[k * HDIM + n] : 0.f;
        w1t_m[gid] = f2bf(v); return;
    } gid -= S1;
    if (gid < S2) {
        int n = gid / 160, k = gid % 160;
        float v = (k < HDIM && n < HDIM) ? sW2[k * HDIM + n] : 0.f;
        w2t_m[gid] = f2bf(v); return;
    } gid -= S2;
    if (gid < S3) { w3_m[gid] = (gid < HDIM) ? f2bf(sW3[gid]) : (unsigned short)0; return; } gid -= S3;
    if (gid < S4) {
        int n = gid / 448, k = gid % 448;
        float v = (k < D_STATE && n < HDIM) ? aW1[k * HDIM + n] : 0.f;
        w1t_a[gid] = f2bf(v); return;
    } gid -= S4;
    if (gid < S5) {
        int n = gid / 160, k = gid % 160;
        float v = (k < HDIM && n < HDIM) ? aW2[k * HDIM + n] : 0.f;
        w2t_a[gid] = f2bf(v); return;
    } gid -= S5;
    if (gid < S6) { w3_a[gid] = (gid < HDIM) ? f2bf(aW3[gid]) : (unsigned short)0; }
}

// ---------------------------------------------------------------------------
// Attention MLP (proven, unchanged): A [M][K] f32 -> out [M]
// ---------------------------------------------------------------------------
template <int K, int NT>
__global__ __launch_bounds__(256) void mlp_mfma(
    const float* __restrict__ A,
    const unsigned short* __restrict__ w1t, const float* __restrict__ b1,
    const unsigned short* __restrict__ w2t, const float* __restrict__ b2,
    const unsigned short* __restrict__ w3, const float* __restrict__ b3,
    float* __restrict__ out)
{
    constexpr int KP = NT * 64;
    __shared__ __align__(16) char smem[43008];
    const int SB_OFF = 16384;

    const int tid = threadIdx.x;
    const int w = tid >> 6;
    const int l = tid & 63;
    const int l15 = l & 15;
    const int lg = l >> 4;
    const int row0 = blockIdx.x * 128;

    const int arow = tid >> 1;
    const int acb = (tid & 1) * 32;

    f32x4 acc[2][10];
#pragma unroll
    for (int rf = 0; rf < 2; ++rf)
#pragma unroll
        for (int nf = 0; nf < 10; ++nf) acc[rf][nf] = (f32x4){0.f, 0.f, 0.f, 0.f};

    const int arow_base = w * 32 + l15;
    const int asw = (arow_base & 7) << 4;

    for (int t = 0; t < NT; ++t) {
        const int k0 = t * 64;
        __syncthreads();

        unsigned short tmp[32];
        if (k0 + 64 <= K) {
            const float* src = A + (size_t)(row0 + arow) * K + k0 + acb;
#pragma unroll
            for (int i = 0; i < 16; ++i) {
                float2 v = ((const float2*)src)[i];
                tmp[2 * i] = f2bf(v.x);
                tmp[2 * i + 1] = f2bf(v.y);
            }
        } else {
            const float* arp = A + (size_t)(row0 + arow) * K;
#pragma unroll
            for (int i = 0; i < 32; ++i) {
                int col = k0 + acb + i;
                tmp[i] = (col < K) ? f2bf(arp[col]) : (unsigned short)0;
            }
        }
        {
            const int sw = (arow & 7) << 4;
#pragma unroll
            for (int i = 0; i < 4; ++i) {
                s16x8 pv;
#pragma unroll
                for (int j = 0; j < 8; ++j) pv[j] = (short)tmp[i * 8 + j];
                int inrow = acb * 2 + i * 16;
                *(s16x8*)(smem + arow * 128 + (inrow ^ sw)) = pv;
            }
        }

#pragma unroll
        for (int i = 0; i < 5; ++i) {
            int idx = i * 256 + tid;
            int n = idx >> 3, s2 = idx & 7;
            s16x8 v = *(const s16x8*)(w1t + (size_t)n * KP + k0 + s2 * 8);
            int inrow = s2 * 16;
            *(s16x8*)(smem + SB_OFF + n * 128 + (inrow ^ ((n & 7) << 4))) = v;
        }

        __syncthreads();

#pragma unroll
        for (int kc = 0; kc < 2; ++kc) {
            const int inrowA = kc * 64 + lg * 16;
            s16x8 a0 = *(const s16x8*)(smem + arow_base * 128 + (inrowA ^ asw));
            s16x8 a1 = *(const s16x8*)(smem + arow_base * 128 + 2048 + (inrowA ^ asw));
#pragma unroll
            for (int nf = 0; nf < 10; ++nf) {
                const int n = nf * 16 + l15;
                s16x8 b = *(const s16x8*)(smem + SB_OFF + n * 128 + (inrowA ^ ((n & 7) << 4)));
                acc[0][nf] = __builtin_amdgcn_mfma_f32_16x16x32_bf16(a0, b, acc[0][nf], 0, 0, 0);
                acc[1][nf] = __builtin_amdgcn_mfma_f32_16x16x32_bf16(a1, b, acc[1][nf], 0, 0, 0);
            }
        }
    }

    __syncthreads();

    {
        float b1c[10];
#pragma unroll
        for (int nf = 0; nf < 10; ++nf) {
            int col = nf * 16 + l15;
            b1c[nf] = (col < HDIM) ? b1[col] : 0.f;
        }
#pragma unroll
        for (int rf = 0; rf < 2; ++rf)
#pragma unroll
            for (int nf = 0; nf < 10; ++nf)
#pragma unroll
                for (int r = 0; r < 4; ++r) {
                    int row = w * 32 + rf * 16 + lg * 4 + r;
                    int col = nf * 16 + l15;
                    float h = fmaxf(acc[rf][nf][r] + b1c[nf], 0.f);
                    *(unsigned short*)(smem + row * 336 + col * 2) = f2bf(h);
                }
    }
    __syncthreads();

    f32x4 acc2[2][10];
#pragma unroll
    for (int rf = 0; rf < 2; ++rf)
#pragma unroll
        for (int nf = 0; nf < 10; ++nf) acc2[rf][nf] = (f32x4){0.f, 0.f, 0.f, 0.f};

#pragma unroll
    for (int kc = 0; kc < 5; ++kc) {
        s16x8 a0 = *(const s16x8*)(smem + (w * 32 + l15) * 336 + kc * 64 + lg * 16);
        s16x8 a1 = *(const s16x8*)(smem + (w * 32 + 16 + l15) * 336 + kc * 64 + lg * 16);
#pragma unroll
        for (int nf = 0; nf < 10; ++nf) {
            const int n = nf * 16 + l15;
            s16x8 b = *(const s16x8*)(w2t + n * 160 + kc * 32 + lg * 8);
            acc2[0][nf] = __builtin_amdgcn_mfma_f32_16x16x32_bf16(a0, b, acc2[0][nf], 0, 0, 0);
            acc2[1][nf] = __builtin_amdgcn_mfma_f32_16x16x32_bf16(a1, b, acc2[1][nf], 0, 0, 0);
        }
    }

    {
        float b2c[10], w3c[10];
#pragma unroll
        for (int nf = 0; nf < 10; ++nf) {
            int col = nf * 16 + l15;
            b2c[nf] = (col < HDIM) ? b2[col] : 0.f;
            w3c[nf] = bf2f(w3[col]);
        }
#pragma unroll
        for (int rf = 0; rf < 2; ++rf)
#pragma unroll
            for (int r = 0; r < 4; ++r) {
                float ps = 0.f;
#pragma unroll
                for (int nf = 0; nf < 10; ++nf)
                    ps += fmaxf(acc2[rf][nf][r] + b2c[nf], 0.f) * w3c[nf];
                ps += __shfl_xor(ps, 1);
                ps += __shfl_xor(ps, 2);
                ps += __shfl_xor(ps, 4);
                ps += __shfl_xor(ps, 8);
                if (l15 == 0)
                    out[row0 + w * 32 + rf * 16 + lg * 4 + r] = ps + b3[0];
            }
    }
}

// ---------------------------------------------------------------------------
// Barrier-free fused mention kernel (register GEMM).
// Lane l of wave w owns span rows {w*32+(l&15), +16}; builds its own A
// fragments in registers (f32 -> gi store -> bf16 pack), reads B fragments
// straight from L2-resident w1t. NO __syncthreads in the K-loop.
// ---------------------------------------------------------------------------
__device__ __forceinline__ void build_win(
    int j0, const float* __restrict__ sp1, const float* __restrict__ sp2,
    const float* __restrict__ em1, const float* __restrict__ em2,
    const float* __restrict__ wt, float w0, float w1v, float* v)
{
    if (j0 + 8 <= 400) {
        float4 q0 = *(const float4*)(sp1 + j0);
        float4 q1 = *(const float4*)(sp1 + j0 + 4);
        v[0] = q0.x; v[1] = q0.y; v[2] = q0.z; v[3] = q0.w;
        v[4] = q1.x; v[5] = q1.y; v[6] = q1.z; v[7] = q1.w;
    } else if (j0 >= 400 && j0 + 8 <= 800) {
        const int jj = j0 - 400;
        float4 q0 = *(const float4*)(sp2 + jj);
        float4 q1 = *(const float4*)(sp2 + jj + 4);
        v[0] = q0.x; v[1] = q0.y; v[2] = q0.z; v[3] = q0.w;
        v[4] = q1.x; v[5] = q1.y; v[6] = q1.z; v[7] = q1.w;
    } else if (j0 >= 800 && j0 + 8 <= 1144) {
        const int jj = j0 - 800;
#pragma unroll
        for (int q = 0; q < 4; ++q) {
            float2 ea = *(const float2*)(em1 + jj + 2 * q);
            float2 eb = *(const float2*)(em2 + jj + 2 * q);
            v[2 * q]     = w0 * ea.x + w1v * eb.x;
            v[2 * q + 1] = w0 * ea.y + w1v * eb.y;
        }
    } else {
#pragma unroll
        for (int q = 0; q < 8; ++q) {
            const int j = j0 + q;
            float val;
            if (j < 400) val = sp1[j];
            else if (j < 800) val = sp2[j - 400];
            else if (j < 1150) val = w0 * em1[j - 800] + w1v * em2[j - 800];
            else if (j < GI_DIM) val = wt[j - 1150];
            else val = 0.f;
            v[q] = val;
        }
    }
}

__global__ __launch_bounds__(256) void mention_reg(
    const float* __restrict__ states, const float* __restrict__ embeds,
    const int* __restrict__ starts, const int* __restrict__ widths,
    const float* __restrict__ alfa, const float* __restrict__ wtab,
    const unsigned short* __restrict__ w1t, const float* __restrict__ b1,
    const unsigned short* __restrict__ w2t, const float* __restrict__ b2,
    const unsigned short* __restrict__ w3, const float* __restrict__ b3,
    float* __restrict__ gi, float* __restrict__ out)
{
    __shared__ __align__(16) char smem[43008];   // h1 only: [128][336B]

    const int tid = threadIdx.x;
    const int w = tid >> 6;
    const int l = tid & 63;
    const int l15 = l & 15;
    const int lg = l >> 4;
    const int row0 = blockIdx.x * 128;

    // two spans per lane
    const int srA = row0 + w * 32 + l15;
    const int srB = srA + 16;

    const int i1A = starts[srA], wdA = widths[srA];
    const int i1B = starts[srB], wdB = widths[srB];
    int i2A = i1A + wdA; if (i2A > N_T - 1) i2A = N_T - 1;
    int ieA = i1A + 1;   if (ieA > N_T - 1) ieA = N_T - 1;
    int i2B = i1B + wdB; if (i2B > N_T - 1) i2B = N_T - 1;
    int ieB = i1B + 1;   if (ieB > N_T - 1) ieB = N_T - 1;

    const float e0A = expf(alfa[i1A]);
    const float e1A = (wdA > 0) ? expf(alfa[ieA]) : 0.0f;
    const float invA = 1.0f / (e0A + e1A);
    const float w0A = e0A * invA, w1A = e1A * invA;
    const float e0B = expf(alfa[i1B]);
    const float e1B = (wdB > 0) ? expf(alfa[ieB]) : 0.0f;
    const float invB = 1.0f / (e0B + e1B);
    const float w0B = e0B * invB, w1B = e1B * invB;

    const float* __restrict__ sp1A = states + (size_t)i1A * D_STATE;
    const float* __restrict__ sp2A = states + (size_t)i2A * D_STATE;
    const float* __restrict__ em1A = embeds + (size_t)i1A * D_EMB;
    const float* __restrict__ em2A = embeds + (size_t)ieA * D_EMB;
    const float* __restrict__ wtA  = wtab + (size_t)(wdA + 1) * D_DIST;
    const float* __restrict__ sp1B = states + (size_t)i1B * D_STATE;
    const float* __restrict__ sp2B = states + (size_t)i2B * D_STATE;
    const float* __restrict__ em1B = embeds + (size_t)i1B * D_EMB;
    const float* __restrict__ em2B = embeds + (size_t)ieB * D_EMB;
    const float* __restrict__ wtB  = wtab + (size_t)(wdB + 1) * D_DIST;
    float* __restrict__ growA = gi + (size_t)srA * GI_DIM;
    float* __restrict__ growB = gi + (size_t)srB * GI_DIM;

    const unsigned short* __restrict__ bbase = w1t + (size_t)l15 * 1216;

    f32x4 acc[2][10];
#pragma unroll
    for (int rf = 0; rf < 2; ++rf)
#pragma unroll
        for (int nf = 0; nf < 10; ++nf) acc[rf][nf] = (f32x4){0.f, 0.f, 0.f, 0.f};

    for (int t = 0; t < 19; ++t) {
#pragma unroll
        for (int kc = 0; kc < 2; ++kc) {
            const int j0 = t * 64 + kc * 32 + lg * 8;

            float vA[8], vB[8];
            build_win(j0, sp1A, sp2A, em1A, em2A, wtA, w0A, w1A, vA);
            build_win(j0, sp1B, sp2B, em1B, em2B, wtB, w0B, w1B, vB);

            // f32 g_i stores (8B-aligned float2; tail window clipped at 1170)
            if (j0 + 8 <= GI_DIM) {
#pragma unroll
                for (int q = 0; q < 4; ++q) {
                    *(float2*)(growA + j0 + 2 * q) = (float2){vA[2 * q], vA[2 * q + 1]};
                    *(float2*)(growB + j0 + 2 * q) = (float2){vB[2 * q], vB[2 * q + 1]};
                }
            } else if (j0 < GI_DIM) {
#pragma unroll
                for (int q = 0; q < 4; ++q) {
                    if (j0 + 2 * q + 2 <= GI_DIM) {
                        *(float2*)(growA + j0 + 2 * q) = (float2){vA[2 * q], vA[2 * q + 1]};
                        *(float2*)(growB + j0 + 2 * q) = (float2){vB[2 * q], vB[2 * q + 1]};
                    }
                }
            }

            // pack A fragments
            s16x8 a0, a1;
#pragma unroll
            for (int q = 0; q < 8; ++q) {
                a0[q] = (short)f2bf(vA[q]);
                a1[q] = (short)f2bf(vB[q]);
            }

            // B fragments straight from L2-resident w1t; MFMA
#pragma unroll
            for (int nf = 0; nf < 10; ++nf) {
                s16x8 b = *(const s16x8*)(bbase + (size_t)nf * 19456 + j0);
                acc[0][nf] = __builtin_amdgcn_mfma_f32_16x16x32_bf16(a0, b, acc[0][nf], 0, 0, 0);
                acc[1][nf] = __builtin_amdgcn_mfma_f32_16x16x32_bf16(a1, b, acc[1][nf], 0, 0, 0);
            }
        }
    }

    // ---- h1 = relu(acc + b1) -> sH bf16 [128][336B]  (per-wave rows) ----
    {
        float b1c[10];
#pragma unroll
        for (int nf = 0; nf < 10; ++nf) {
            int col = nf * 16 + l15;
            b1c[nf] = (col < HDIM) ? b1[col] : 0.f;
        }
#pragma unroll
        for (int rf = 0; rf < 2; ++rf)
#pragma unroll
            for (int nf = 0; nf < 10; ++nf)
#pragma unroll
                for (int r = 0; r < 4; ++r) {
                    int row = w * 32 + rf * 16 + lg * 4 + r;
                    int col = nf * 16 + l15;
                    float h = fmaxf(acc[rf][nf][r] + b1c[nf], 0.f);
                    *(unsigned short*)(smem + row * 336 + col * 2) = f2bf(h);
                }
    }
    __syncthreads();

    // ---- layer 2 ----
    f32x4 acc2[2][10];
#pragma unroll
    for (int rf = 0; rf < 2; ++rf)
#pragma unroll
        for (int nf = 0; nf < 10; ++nf) acc2[rf][nf] = (f32x4){0.f, 0.f, 0.f, 0.f};

#pragma unroll
    for (int kc = 0; kc < 5; ++kc) {
        s16x8 a0 = *(const s16x8*)(smem + (w * 32 + l15) * 336 + kc * 64 + lg * 16);
        s16x8 a1 = *(const s16x8*)(smem + (w * 32 + 16 + l15) * 336 + kc * 64 + lg * 16);
#pragma unroll
        for (int nf = 0; nf < 10; ++nf) {
            const int n = nf * 16 + l15;
            s16x8 b = *(const s16x8*)(w2t + n * 160 + kc * 32 + lg * 8);
            acc2[0][nf] = __builtin_amdgcn_mfma_f32_16x16x32_bf16(a0, b, acc2[0][nf], 0, 0, 0);
            acc2[1][nf] = __builtin_amdgcn_mfma_f32_16x16x32_bf16(a1, b, acc2[1][nf], 0, 0, 0);
        }
    }

    // ---- layer 3 ----
    {
        float b2c[10], w3c[10];
#pragma unroll
        for (int nf = 0; nf < 10; ++nf) {
            int col = nf * 16 + l15;
            b2c[nf] = (col < HDIM) ? b2[col] : 0.f;
            w3c[nf] = bf2f(w3[col]);
        }
#pragma unroll
        for (int rf = 0; rf < 2; ++rf)
#pragma unroll
            for (int r = 0; r < 4; ++r) {
                float ps = 0.f;
#pragma unroll
                for (int nf = 0; nf < 10; ++nf)
                    ps += fmaxf(acc2[rf][nf][r] + b2c[nf], 0.f) * w3c[nf];
                ps += __shfl_xor(ps, 1);
                ps += __shfl_xor(ps, 2);
                ps += __shfl_xor(ps, 4);
                ps += __shfl_xor(ps, 8);
                if (l15 == 0)
                    out[row0 + w * 32 + rf * 16 + lg * 4 + r] = ps + b3[0];
            }
    }
}

extern "C" void kernel_launch(void* const* d_in, const int* in_sizes, int n_in,
                              void* d_out, int out_size, void* d_ws, size_t ws_size,
                              hipStream_t stream)
{
    const float* states = (const float*)d_in[0];
    const float* embeds = (const float*)d_in[1];
    const int*   starts = (const int*)d_in[2];
    const int*   widths = (const int*)d_in[3];
    const float* aW1 = (const float*)d_in[4];
    const float* ab1 = (const float*)d_in[5];
    const float* aW2 = (const float*)d_in[6];
    const float* ab2 = (const float*)d_in[7];
    const float* aW3 = (const float*)d_in[8];
    const float* ab3 = (const float*)d_in[9];
    const float* wtab = (const float*)d_in[10];
    const float* sW1 = (const float*)d_in[11];
    const float* sb1 = (const float*)d_in[12];
    const float* sW2 = (const float*)d_in[13];
    const float* sb2 = (const float*)d_in[14];
    const float* sW3 = (const float*)d_in[15];
    const float* sb3 = (const float*)d_in[16];

    float* gi = (float*)d_out;
    float* scores = gi + (size_t)N_S * GI_DIM;

    char* ws = (char*)d_ws;
    float* alfa = (float*)ws;                                   // 320000 B
    unsigned short* w1t_m = (unsigned short*)(ws + 320512);
    unsigned short* w2t_m = (unsigned short*)(ws + 709632);
    unsigned short* w3_m  = (unsigned short*)(ws + 760832);
    unsigned short* w1t_a = (unsigned short*)(ws + 761344);
    unsigned short* w2t_a = (unsigned short*)(ws + 904704);
    unsigned short* w3_a  = (unsigned short*)(ws + 955904);

    // 0) convert/transpose/pad weights to bf16
    convert_kernel<<<1242, 256, 0, stream>>>(sW1, sW2, sW3, aW1, aW2, aW3,
                                             w1t_m, w2t_m, w3_m, w1t_a, w2t_a, w3_a);

    // 1) alfa = attention-MLP(states)
    mlp_mfma<D_STATE, 7><<<N_T / 128, 256, 0, stream>>>(
        states, w1t_a, ab1, w2t_a, ab2, w3_a, ab3, alfa);

    // 2+3) fused barrier-free: g_i assembly + mention MLP
    mention_reg<<<N_S / 128, 256, 0, stream>>>(
        states, embeds, starts, widths, alfa, wtab,
        w1t_m, sb1, w2t_m, sb2, w3_m, sb3, gi, scores);
}

// Round 5
// 723.088 us; speedup vs baseline: 12.1378x; 1.0039x over previous
//
#include <hip/hip_runtime.h>
#include <math.h>

#define N_T 80000
#define N_S 160000
#define D_STATE 400
#define D_EMB 350
#define D_DIST 20
#define HDIM 150
#define GI_DIM 1170
#define KP16 1216   // padded K for bf16 shadow / weights

typedef __attribute__((ext_vector_type(8))) short s16x8;
typedef __attribute__((ext_vector_type(4))) float f32x4;

__device__ __forceinline__ unsigned short f2bf(float f) {
    union { float f; unsigned int u; } c; c.f = f;
    unsigned int u = c.u;
    unsigned int r = (u + 0x7fffu + ((u >> 16) & 1u)) >> 16;  // RNE
    return (unsigned short)r;
}
__device__ __forceinline__ float bf2f(unsigned short h) {
    union { unsigned int u; float f; } c; c.u = ((unsigned int)h) << 16;
    return c.f;
}

// ---------------------------------------------------------------------------
// Weight conversion: f32 [K][150] -> bf16 transposed+padded [160][KP]
// ---------------------------------------------------------------------------
__global__ __launch_bounds__(256) void convert_kernel(
    const float* __restrict__ sW1, const float* __restrict__ sW2, const float* __restrict__ sW3,
    const float* __restrict__ aW1, const float* __restrict__ aW2, const float* __restrict__ aW3,
    unsigned short* __restrict__ w1t_m, unsigned short* __restrict__ w2t_m, unsigned short* __restrict__ w3_m,
    unsigned short* __restrict__ w1t_a, unsigned short* __restrict__ w2t_a, unsigned short* __restrict__ w3_a)
{
    int gid = blockIdx.x * 256 + threadIdx.x;
    const int S1 = 160 * 1216, S2 = 160 * 160, S3 = 160, S4 = 160 * 448, S5 = 160 * 160, S6 = 160;
    if (gid < S1) {
        int n = gid / 1216, k = gid % 1216;
        float v = (k < GI_DIM && n < HDIM) ? sW1[k * HDIM + n] : 0.f;
        w1t_m[gid] = f2bf(v); return;
    } gid -= S1;
    if (gid < S2) {
        int n = gid / 160, k = gid % 160;
        float v = (k < HDIM && n < HDIM) ? sW2[k * HDIM + n] : 0.f;
        w2t_m[gid] = f2bf(v); return;
    } gid -= S2;
    if (gid < S3) { w3_m[gid] = (gid < HDIM) ? f2bf(sW3[gid]) : (unsigned short)0; return; } gid -= S3;
    if (gid < S4) {
        int n = gid / 448, k = gid % 448;
        float v = (k < D_STATE && n < HDIM) ? aW1[k * HDIM + n] : 0.f;
        w1t_a[gid] = f2bf(v); return;
    } gid -= S4;
    if (gid < S5) {
        int n = gid / 160, k = gid % 160;
        float v = (k < HDIM && n < HDIM) ? aW2[k * HDIM + n] : 0.f;
        w2t_a[gid] = f2bf(v); return;
    } gid -= S5;
    if (gid < S6) { w3_a[gid] = (gid < HDIM) ? f2bf(aW3[gid]) : (unsigned short)0; }
}

// ---------------------------------------------------------------------------
// g_i build: one wave per span. Writes f32 g_i (output) and optionally a
// bf16 shadow [N_S][1216] (zero-padded K) for the GEMM. No LDS, no acc
// registers -> high occupancy, compiler pipelines the float2 stream.
// ---------------------------------------------------------------------------
template <int W16>
__global__ __launch_bounds__(256) void gi_build(
    const float* __restrict__ states, const float* __restrict__ embeds,
    const int* __restrict__ starts, const int* __restrict__ widths,
    const float* __restrict__ alfa, const float* __restrict__ wtab,
    float* __restrict__ gi, unsigned short* __restrict__ gi16)
{
    const int wave = threadIdx.x >> 6;
    const int lane = threadIdx.x & 63;
    const int s = blockIdx.x * 4 + wave;

    const int i1 = starts[s];
    const int wdt = widths[s];
    int i2 = i1 + wdt; if (i2 > N_T - 1) i2 = N_T - 1;
    int ie = i1 + 1;  if (ie > N_T - 1) ie = N_T - 1;

    const float e0 = expf(alfa[i1]);
    const float e1 = (wdt > 0) ? expf(alfa[ie]) : 0.0f;
    const float inv = 1.0f / (e0 + e1);
    const float w0 = e0 * inv;
    const float w1v = e1 * inv;

    const float* __restrict__ sp1 = states + (size_t)i1 * D_STATE;
    const float* __restrict__ sp2 = states + (size_t)i2 * D_STATE;
    const float* __restrict__ em1 = embeds + (size_t)i1 * D_EMB;
    const float* __restrict__ em2 = embeds + (size_t)ie * D_EMB;
    const float* __restrict__ wt = wtab + (size_t)(wdt + 1) * D_DIST;
    float* __restrict__ grow = gi + (size_t)s * GI_DIM;
    unsigned short* __restrict__ hrow = W16 ? (gi16 + (size_t)s * KP16) : (unsigned short*)0;

    for (int j2 = lane; j2 < KP16 / 2; j2 += 64) {
        const int j = j2 * 2;
        float x, y;
        if (j + 2 <= 400) {
            float2 v = *(const float2*)(sp1 + j); x = v.x; y = v.y;
        } else if (j >= 400 && j + 2 <= 800) {
            float2 v = *(const float2*)(sp2 + j - 400); x = v.x; y = v.y;
        } else if (j >= 800 && j + 2 <= 1150) {
            float2 a = *(const float2*)(em1 + j - 800);
            float2 b = *(const float2*)(em2 + j - 800);
            x = w0 * a.x + w1v * b.x;
            y = w0 * a.y + w1v * b.y;
        } else {
            float vv[2];
#pragma unroll
            for (int q = 0; q < 2; ++q) {
                const int jq = j + q;
                float val;
                if (jq < 400) val = sp1[jq];
                else if (jq < 800) val = sp2[jq - 400];
                else if (jq < 1150) val = w0 * em1[jq - 800] + w1v * em2[jq - 800];
                else if (jq < GI_DIM) val = wt[jq - 1150];
                else val = 0.f;
                vv[q] = val;
            }
            x = vv[0]; y = vv[1];
        }
        if (j < GI_DIM) *(float2*)(grow + j) = make_float2(x, y);  // 1170 even -> pairs never straddle
        if (W16) {
            unsigned int packed = (unsigned int)f2bf(x) | ((unsigned int)f2bf(y) << 16);
            *(unsigned int*)(hrow + j) = packed;
        }
    }
}

// ---------------------------------------------------------------------------
// Clean bf16 GEMM + fused MLP layers 2/3: A16 [N_S][1216] bf16, branch-free
// batched staging with next-tile register prefetch (T14).
// ---------------------------------------------------------------------------
__global__ __launch_bounds__(256) void mention_gemm(
    const unsigned short* __restrict__ A16,
    const unsigned short* __restrict__ w1t, const float* __restrict__ b1,
    const unsigned short* __restrict__ w2t, const float* __restrict__ b2,
    const unsigned short* __restrict__ w3, const float* __restrict__ b3,
    float* __restrict__ out)
{
    __shared__ __align__(16) char smem[43008];
    const int SB_OFF = 16384;

    const int tid = threadIdx.x;
    const int w = tid >> 6;
    const int l = tid & 63;
    const int l15 = l & 15;
    const int lg = l >> 4;
    const int row0 = blockIdx.x * 128;

    f32x4 acc[2][10];
#pragma unroll
    for (int rf = 0; rf < 2; ++rf)
#pragma unroll
        for (int nf = 0; nf < 10; ++nf) acc[rf][nf] = (f32x4){0.f, 0.f, 0.f, 0.f};

    const int arow_base = w * 32 + l15;
    const int asw = (arow_base & 7) << 4;

    // batched staging registers (issue all loads back-to-back)
    s16x8 va[4], vb[5];
    {
        const int k0 = 0;
#pragma unroll
        for (int i = 0; i < 4; ++i) {
            int j = i * 256 + tid; int row = j >> 3, sub = j & 7;
            va[i] = *(const s16x8*)(A16 + (size_t)(row0 + row) * KP16 + k0 + sub * 8);
        }
#pragma unroll
        for (int i = 0; i < 5; ++i) {
            int idx = i * 256 + tid; int n = idx >> 3, s2 = idx & 7;
            vb[i] = *(const s16x8*)(w1t + (size_t)n * KP16 + k0 + s2 * 8);
        }
    }

    for (int t = 0; t < 19; ++t) {
        __syncthreads();   // all waves done reading previous LDS tile

        // ds_write staged registers (swizzled)
#pragma unroll
        for (int i = 0; i < 4; ++i) {
            int j = i * 256 + tid; int row = j >> 3, sub = j & 7;
            *(s16x8*)(smem + row * 128 + ((sub * 16) ^ ((row & 7) << 4))) = va[i];
        }
#pragma unroll
        for (int i = 0; i < 5; ++i) {
            int idx = i * 256 + tid; int n = idx >> 3, s2 = idx & 7;
            *(s16x8*)(smem + SB_OFF + n * 128 + ((s2 * 16) ^ ((n & 7) << 4))) = vb[i];
        }
        __syncthreads();

        // prefetch next tile (lands during MFMA phase)
        if (t + 1 < 19) {
            const int k0 = (t + 1) * 64;
#pragma unroll
            for (int i = 0; i < 4; ++i) {
                int j = i * 256 + tid; int row = j >> 3, sub = j & 7;
                va[i] = *(const s16x8*)(A16 + (size_t)(row0 + row) * KP16 + k0 + sub * 8);
            }
#pragma unroll
            for (int i = 0; i < 5; ++i) {
                int idx = i * 256 + tid; int n = idx >> 3, s2 = idx & 7;
                vb[i] = *(const s16x8*)(w1t + (size_t)n * KP16 + k0 + s2 * 8);
            }
        }

        // MFMA phase
#pragma unroll
        for (int kc = 0; kc < 2; ++kc) {
            const int inrowA = kc * 64 + lg * 16;
            s16x8 a0 = *(const s16x8*)(smem + arow_base * 128 + (inrowA ^ asw));
            s16x8 a1 = *(const s16x8*)(smem + arow_base * 128 + 2048 + (inrowA ^ asw));
#pragma unroll
            for (int nf = 0; nf < 10; ++nf) {
                const int n = nf * 16 + l15;
                s16x8 b = *(const s16x8*)(smem + SB_OFF + n * 128 + (inrowA ^ ((n & 7) << 4)));
                acc[0][nf] = __builtin_amdgcn_mfma_f32_16x16x32_bf16(a0, b, acc[0][nf], 0, 0, 0);
                acc[1][nf] = __builtin_amdgcn_mfma_f32_16x16x32_bf16(a1, b, acc[1][nf], 0, 0, 0);
            }
        }
    }

    __syncthreads();  // done with sA/sB, reuse as h1 buffer

    // ---- h1 = relu(acc + b1) -> LDS bf16 [128][336B] ----
    {
        float b1c[10];
#pragma unroll
        for (int nf = 0; nf < 10; ++nf) {
            int col = nf * 16 + l15;
            b1c[nf] = (col < HDIM) ? b1[col] : 0.f;
        }
#pragma unroll
        for (int rf = 0; rf < 2; ++rf)
#pragma unroll
            for (int nf = 0; nf < 10; ++nf)
#pragma unroll
                for (int r = 0; r < 4; ++r) {
                    int row = w * 32 + rf * 16 + lg * 4 + r;
                    int col = nf * 16 + l15;
                    float h = fmaxf(acc[rf][nf][r] + b1c[nf], 0.f);
                    *(unsigned short*)(smem + row * 336 + col * 2) = f2bf(h);
                }
    }
    __syncthreads();

    // ---- layer 2 ----
    f32x4 acc2[2][10];
#pragma unroll
    for (int rf = 0; rf < 2; ++rf)
#pragma unroll
        for (int nf = 0; nf < 10; ++nf) acc2[rf][nf] = (f32x4){0.f, 0.f, 0.f, 0.f};

#pragma unroll
    for (int kc = 0; kc < 5; ++kc) {
        s16x8 a0 = *(const s16x8*)(smem + (w * 32 + l15) * 336 + kc * 64 + lg * 16);
        s16x8 a1 = *(const s16x8*)(smem + (w * 32 + 16 + l15) * 336 + kc * 64 + lg * 16);
#pragma unroll
        for (int nf = 0; nf < 10; ++nf) {
            const int n = nf * 16 + l15;
            s16x8 b = *(const s16x8*)(w2t + n * 160 + kc * 32 + lg * 8);
            acc2[0][nf] = __builtin_amdgcn_mfma_f32_16x16x32_bf16(a0, b, acc2[0][nf], 0, 0, 0);
            acc2[1][nf] = __builtin_amdgcn_mfma_f32_16x16x32_bf16(a1, b, acc2[1][nf], 0, 0, 0);
        }
    }

    // ---- layer 3 ----
    {
        float b2c[10], w3c[10];
#pragma unroll
        for (int nf = 0; nf < 10; ++nf) {
            int col = nf * 16 + l15;
            b2c[nf] = (col < HDIM) ? b2[col] : 0.f;
            w3c[nf] = bf2f(w3[col]);
        }
#pragma unroll
        for (int rf = 0; rf < 2; ++rf)
#pragma unroll
            for (int r = 0; r < 4; ++r) {
                float ps = 0.f;
#pragma unroll
                for (int nf = 0; nf < 10; ++nf)
                    ps += fmaxf(acc2[rf][nf][r] + b2c[nf], 0.f) * w3c[nf];
                ps += __shfl_xor(ps, 1);
                ps += __shfl_xor(ps, 2);
                ps += __shfl_xor(ps, 4);
                ps += __shfl_xor(ps, 8);
                if (l15 == 0)
                    out[row0 + w * 32 + rf * 16 + lg * 4 + r] = ps + b3[0];
            }
    }
}

// ---------------------------------------------------------------------------
// Fallback / alfa MLP (proven round-2 kernel): A [M][K] f32 -> out [M]
// ---------------------------------------------------------------------------
template <int K, int NT>
__global__ __launch_bounds__(256) void mlp_mfma(
    const float* __restrict__ A,
    const unsigned short* __restrict__ w1t, const float* __restrict__ b1,
    const unsigned short* __restrict__ w2t, const float* __restrict__ b2,
    const unsigned short* __restrict__ w3, const float* __restrict__ b3,
    float* __restrict__ out)
{
    constexpr int KP = NT * 64;
    __shared__ __align__(16) char smem[43008];
    const int SB_OFF = 16384;

    const int tid = threadIdx.x;
    const int w = tid >> 6;
    const int l = tid & 63;
    const int l15 = l & 15;
    const int lg = l >> 4;
    const int row0 = blockIdx.x * 128;

    const int arow = tid >> 1;
    const int acb = (tid & 1) * 32;

    f32x4 acc[2][10];
#pragma unroll
    for (int rf = 0; rf < 2; ++rf)
#pragma unroll
        for (int nf = 0; nf < 10; ++nf) acc[rf][nf] = (f32x4){0.f, 0.f, 0.f, 0.f};

    const int arow_base = w * 32 + l15;
    const int asw = (arow_base & 7) << 4;

    for (int t = 0; t < NT; ++t) {
        const int k0 = t * 64;
        __syncthreads();

        unsigned short tmp[32];
        if (k0 + 64 <= K) {
            const float* src = A + (size_t)(row0 + arow) * K + k0 + acb;
#pragma unroll
            for (int i = 0; i < 16; ++i) {
                float2 v = ((const float2*)src)[i];
                tmp[2 * i] = f2bf(v.x);
                tmp[2 * i + 1] = f2bf(v.y);
            }
        } else {
            const float* arp = A + (size_t)(row0 + arow) * K;
#pragma unroll
            for (int i = 0; i < 32; ++i) {
                int col = k0 + acb + i;
                tmp[i] = (col < K) ? f2bf(arp[col]) : (unsigned short)0;
            }
        }
        {
            const int sw = (arow & 7) << 4;
#pragma unroll
            for (int i = 0; i < 4; ++i) {
                s16x8 pv;
#pragma unroll
                for (int j = 0; j < 8; ++j) pv[j] = (short)tmp[i * 8 + j];
                int inrow = acb * 2 + i * 16;
                *(s16x8*)(smem + arow * 128 + (inrow ^ sw)) = pv;
            }
        }

#pragma unroll
        for (int i = 0; i < 5; ++i) {
            int idx = i * 256 + tid;
            int n = idx >> 3, s2 = idx & 7;
            s16x8 v = *(const s16x8*)(w1t + (size_t)n * KP + k0 + s2 * 8);
            int inrow = s2 * 16;
            *(s16x8*)(smem + SB_OFF + n * 128 + (inrow ^ ((n & 7) << 4))) = v;
        }

        __syncthreads();

#pragma unroll
        for (int kc = 0; kc < 2; ++kc) {
            const int inrowA = kc * 64 + lg * 16;
            s16x8 a0 = *(const s16x8*)(smem + arow_base * 128 + (inrowA ^ asw));
            s16x8 a1 = *(const s16x8*)(smem + arow_base * 128 + 2048 + (inrowA ^ asw));
#pragma unroll
            for (int nf = 0; nf < 10; ++nf) {
                const int n = nf * 16 + l15;
                s16x8 b = *(const s16x8*)(smem + SB_OFF + n * 128 + (inrowA ^ ((n & 7) << 4)));
                acc[0][nf] = __builtin_amdgcn_mfma_f32_16x16x32_bf16(a0, b, acc[0][nf], 0, 0, 0);
                acc[1][nf] = __builtin_amdgcn_mfma_f32_16x16x32_bf16(a1, b, acc[1][nf], 0, 0, 0);
            }
        }
    }

    __syncthreads();

    {
        float b1c[10];
#pragma unroll
        for (int nf = 0; nf < 10; ++nf) {
            int col = nf * 16 + l15;
            b1c[nf] = (col < HDIM) ? b1[col] : 0.f;
        }
#pragma unroll
        for (int rf = 0; rf < 2; ++rf)
#pragma unroll
            for (int nf = 0; nf < 10; ++nf)
#pragma unroll
                for (int r = 0; r < 4; ++r) {
                    int row = w * 32 + rf * 16 + lg * 4 + r;
                    int col = nf * 16 + l15;
                    float h = fmaxf(acc[rf][nf][r] + b1c[nf], 0.f);
                    *(unsigned short*)(smem + row * 336 + col * 2) = f2bf(h);
                }
    }
    __syncthreads();

    f32x4 acc2[2][10];
#pragma unroll
    for (int rf = 0; rf < 2; ++rf)
#pragma unroll
        for (int nf = 0; nf < 10; ++nf) acc2[rf][nf] = (f32x4){0.f, 0.f, 0.f, 0.f};

#pragma unroll
    for (int kc = 0; kc < 5; ++kc) {
        s16x8 a0 = *(const s16x8*)(smem + (w * 32 + l15) * 336 + kc * 64 + lg * 16);
        s16x8 a1 = *(const s16x8*)(smem + (w * 32 + 16 + l15) * 336 + kc * 64 + lg * 16);
#pragma unroll
        for (int nf = 0; nf < 10; ++nf) {
            const int n = nf * 16 + l15;
            s16x8 b = *(const s16x8*)(w2t + n * 160 + kc * 32 + lg * 8);
            acc2[0][nf] = __builtin_amdgcn_mfma_f32_16x16x32_bf16(a0, b, acc2[0][nf], 0, 0, 0);
            acc2[1][nf] = __builtin_amdgcn_mfma_f32_16x16x32_bf16(a1, b, acc2[1][nf], 0, 0, 0);
        }
    }

    {
        float b2c[10], w3c[10];
#pragma unroll
        for (int nf = 0; nf < 10; ++nf) {
            int col = nf * 16 + l15;
            b2c[nf] = (col < HDIM) ? b2[col] : 0.f;
            w3c[nf] = bf2f(w3[col]);
        }
#pragma unroll
        for (int rf = 0; rf < 2; ++rf)
#pragma unroll
            for (int r = 0; r < 4; ++r) {
                float ps = 0.f;
#pragma unroll
                for (int nf = 0; nf < 10; ++nf)
                    ps += fmaxf(acc2[rf][nf][r] + b2c[nf], 0.f) * w3c[nf];
                ps += __shfl_xor(ps, 1);
                ps += __shfl_xor(ps, 2);
                ps += __shfl_xor(ps, 4);
                ps += __shfl_xor(ps, 8);
                if (l15 == 0)
                    out[row0 + w * 32 + rf * 16 + lg * 4 + r] = ps + b3[0];
            }
    }
}

extern "C" void kernel_launch(void* const* d_in, const int* in_sizes, int n_in,
                              void* d_out, int out_size, void* d_ws, size_t ws_size,
                              hipStream_t stream)
{
    const float* states = (const float*)d_in[0];
    const float* embeds = (const float*)d_in[1];
    const int*   starts = (const int*)d_in[2];
    const int*   widths = (const int*)d_in[3];
    const float* aW1 = (const float*)d_in[4];
    const float* ab1 = (const float*)d_in[5];
    const float* aW2 = (const float*)d_in[6];
    const float* ab2 = (const float*)d_in[7];
    const float* aW3 = (const float*)d_in[8];
    const float* ab3 = (const float*)d_in[9];
    const float* wtab = (const float*)d_in[10];
    const float* sW1 = (const float*)d_in[11];
    const float* sb1 = (const float*)d_in[12];
    const float* sW2 = (const float*)d_in[13];
    const float* sb2 = (const float*)d_in[14];
    const float* sW3 = (const float*)d_in[15];
    const float* sb3 = (const float*)d_in[16];

    float* gi = (float*)d_out;
    float* scores = gi + (size_t)N_S * GI_DIM;

    char* ws = (char*)d_ws;
    float* alfa = (float*)ws;                                   // 320000 B
    unsigned short* w1t_m = (unsigned short*)(ws + 320512);     // 389120
    unsigned short* w2t_m = (unsigned short*)(ws + 709632);     // 51200
    unsigned short* w3_m  = (unsigned short*)(ws + 760832);     // 320
    unsigned short* w1t_a = (unsigned short*)(ws + 761344);     // 143360
    unsigned short* w2t_a = (unsigned short*)(ws + 904704);     // 51200
    unsigned short* w3_a  = (unsigned short*)(ws + 955904);     // 320
    const size_t GI16_OFF = 956416;
    const size_t GI16_BYTES = (size_t)N_S * KP16 * 2;           // 389.12 MB
    unsigned short* gi16 = (unsigned short*)(ws + GI16_OFF);
    const bool have_ws = (ws_size >= GI16_OFF + GI16_BYTES);

    // 0) convert/transpose/pad weights to bf16
    convert_kernel<<<1242, 256, 0, stream>>>(sW1, sW2, sW3, aW1, aW2, aW3,
                                             w1t_m, w2t_m, w3_m, w1t_a, w2t_a, w3_a);

    // 1) alfa = attention-MLP(states)
    mlp_mfma<D_STATE, 7><<<N_T / 128, 256, 0, stream>>>(
        states, w1t_a, ab1, w2t_a, ab2, w3_a, ab3, alfa);

    if (have_ws) {
        // 2) g_i build: f32 output + bf16 shadow
        gi_build<1><<<N_S / 4, 256, 0, stream>>>(
            states, embeds, starts, widths, alfa, wtab, gi, gi16);
        // 3) clean bf16 GEMM + MLP layers 2/3
        mention_gemm<<<N_S / 128, 256, 0, stream>>>(
            gi16, w1t_m, sb1, w2t_m, sb2, w3_m, sb3, scores);
    } else {
        // fallback: f32 g_i only, proven round-2 GEMM from f32
        gi_build<0><<<N_S / 4, 256, 0, stream>>>(
            states, embeds, starts, widths, alfa, wtab, gi, (unsigned short*)0);
        mlp_mfma<GI_DIM, 19><<<N_S / 128, 256, 0, stream>>>(
            gi, w1t_m, sb1, w2t_m, sb2, w3_m, sb3, scores);
    }
}

// Round 7
// 508.258 us; speedup vs baseline: 17.2681x; 1.4227x over previous
//
#include <hip/hip_runtime.h>
#include <math.h>

#define N_T 80000
#define N_S 160000
#define D_STATE 400
#define D_EMB 350
#define D_DIST 20
#define HDIM 150
#define GI_DIM 1170
#define KP16 1216   // padded K for bf16 shadow / weights

typedef __attribute__((ext_vector_type(8))) short s16x8;
typedef __attribute__((ext_vector_type(4))) float f32x4;
typedef __attribute__((ext_vector_type(2))) float f32x2;   // clang vector: OK for nontemporal builtins

__device__ __forceinline__ unsigned short f2bf(float f) {
    union { float f; unsigned int u; } c; c.f = f;
    unsigned int u = c.u;
    unsigned int r = (u + 0x7fffu + ((u >> 16) & 1u)) >> 16;  // RNE
    return (unsigned short)r;
}
__device__ __forceinline__ float bf2f(unsigned short h) {
    union { unsigned int u; float f; } c; c.u = ((unsigned int)h) << 16;
    return c.f;
}

// ---------------------------------------------------------------------------
// Weight conversion: f32 [K][150] -> bf16 transposed+padded [160][KP]
// ---------------------------------------------------------------------------
__global__ __launch_bounds__(256) void convert_kernel(
    const float* __restrict__ sW1, const float* __restrict__ sW2, const float* __restrict__ sW3,
    const float* __restrict__ aW1, const float* __restrict__ aW2, const float* __restrict__ aW3,
    unsigned short* __restrict__ w1t_m, unsigned short* __restrict__ w2t_m, unsigned short* __restrict__ w3_m,
    unsigned short* __restrict__ w1t_a, unsigned short* __restrict__ w2t_a, unsigned short* __restrict__ w3_a)
{
    int gid = blockIdx.x * 256 + threadIdx.x;
    const int S1 = 160 * 1216, S2 = 160 * 160, S3 = 160, S4 = 160 * 448, S5 = 160 * 160, S6 = 160;
    if (gid < S1) {
        int n = gid / 1216, k = gid % 1216;
        float v = (k < GI_DIM && n < HDIM) ? sW1[k * HDIM + n] : 0.f;
        w1t_m[gid] = f2bf(v); return;
    } gid -= S1;
    if (gid < S2) {
        int n = gid / 160, k = gid % 160;
        float v = (k < HDIM && n < HDIM) ? sW2[k * HDIM + n] : 0.f;
        w2t_m[gid] = f2bf(v); return;
    } gid -= S2;
    if (gid < S3) { w3_m[gid] = (gid < HDIM) ? f2bf(sW3[gid]) : (unsigned short)0; return; } gid -= S3;
    if (gid < S4) {
        int n = gid / 448, k = gid % 448;
        float v = (k < D_STATE && n < HDIM) ? aW1[k * HDIM + n] : 0.f;
        w1t_a[gid] = f2bf(v); return;
    } gid -= S4;
    if (gid < S5) {
        int n = gid / 160, k = gid % 160;
        float v = (k < HDIM && n < HDIM) ? aW2[k * HDIM + n] : 0.f;
        w2t_a[gid] = f2bf(v); return;
    } gid -= S5;
    if (gid < S6) { w3_a[gid] = (gid < HDIM) ? f2bf(aW3[gid]) : (unsigned short)0; }
}

// ---------------------------------------------------------------------------
// g_i build v2: one wave per span, fixed 5-window float4 layout per lane.
// Phase 1: batch ALL gather loads into registers (deep MLP).
// Phase 2: batch all stores (nontemporal f32 gi + packed bf16 shadow).
// ---------------------------------------------------------------------------
template <int W16>
__global__ __launch_bounds__(256) void gi_build(
    const float* __restrict__ states, const float* __restrict__ embeds,
    const int* __restrict__ starts, const int* __restrict__ widths,
    const float* __restrict__ alfa, const float* __restrict__ wtab,
    float* __restrict__ gi, unsigned short* __restrict__ gi16)
{
    const int wave = threadIdx.x >> 6;
    const int lane = threadIdx.x & 63;
    const int s = blockIdx.x * 4 + wave;

    const int i1 = starts[s];
    const int wdt = widths[s];
    int i2 = i1 + wdt; if (i2 > N_T - 1) i2 = N_T - 1;
    int ie = i1 + 1;  if (ie > N_T - 1) ie = N_T - 1;

    const float e0 = expf(alfa[i1]);
    const float e1 = (wdt > 0) ? expf(alfa[ie]) : 0.0f;
    const float inv = 1.0f / (e0 + e1);
    const float w0 = e0 * inv;
    const float w1v = e1 * inv;

    const float* __restrict__ sp1 = states + (size_t)i1 * D_STATE;
    const float* __restrict__ sp2 = states + (size_t)i2 * D_STATE;
    const float* __restrict__ em1 = embeds + (size_t)i1 * D_EMB;
    const float* __restrict__ em2 = embeds + (size_t)ie * D_EMB;
    const float* __restrict__ wt = wtab + (size_t)(wdt + 1) * D_DIST;
    float* __restrict__ grow = gi + (size_t)s * GI_DIM;
    unsigned short* __restrict__ hrow = W16 ? (gi16 + (size_t)s * KP16) : (unsigned short*)0;

    // ---- phase 1: gather 5 float4 windows per lane (loads batched) ----
    float v[5][4];
#pragma unroll
    for (int i = 0; i < 5; ++i) {
        const int j = (i * 64 + lane) * 4;
        if (j + 4 <= 400) {
            // states[i1] segment; states rows are 16B-aligned (400*4B)
            float4 q = *(const float4*)(sp1 + j);
            v[i][0] = q.x; v[i][1] = q.y; v[i][2] = q.z; v[i][3] = q.w;
        } else if (j >= 400 && j + 4 <= 800) {
            float4 q = *(const float4*)(sp2 + (j - 400));
            v[i][0] = q.x; v[i][1] = q.y; v[i][2] = q.z; v[i][3] = q.w;
        } else if (j >= 800 && j + 4 <= 1148) {
            // attn segment; embeds rows only 8B-aligned (350*4B) -> float2 loads
            const int jj = j - 800;
            float2 a0 = *(const float2*)(em1 + jj);
            float2 a1 = *(const float2*)(em1 + jj + 2);
            float2 b0 = *(const float2*)(em2 + jj);
            float2 b1 = *(const float2*)(em2 + jj + 2);
            v[i][0] = w0 * a0.x + w1v * b0.x;
            v[i][1] = w0 * a0.y + w1v * b0.y;
            v[i][2] = w0 * a1.x + w1v * b1.x;
            v[i][3] = w0 * a1.y + w1v * b1.y;
        } else if (j < KP16) {
            // boundary / width / pad windows (scalar fallback, few lanes)
#pragma unroll
            for (int q = 0; q < 4; ++q) {
                const int jq = j + q;
                float val;
                if (jq < 400) val = sp1[jq];
                else if (jq < 800) val = sp2[jq - 400];
                else if (jq < 1150) val = w0 * em1[jq - 800] + w1v * em2[jq - 800];
                else if (jq < GI_DIM) val = wt[jq - 1150];
                else val = 0.f;
                v[i][q] = val;
            }
        }
    }

    // ---- phase 2: stores batched ----
#pragma unroll
    for (int i = 0; i < 5; ++i) {
        const int j = (i * 64 + lane) * 4;
        if (j >= KP16) continue;
        if (W16) {
            // packed bf16 shadow: 8B store, rows 16B-aligned (1216*2B)
            uint2 p;
            p.x = (unsigned int)f2bf(v[i][0]) | ((unsigned int)f2bf(v[i][1]) << 16);
            p.y = (unsigned int)f2bf(v[i][2]) | ((unsigned int)f2bf(v[i][3]) << 16);
            *(uint2*)(hrow + j) = p;
        }
        // f32 gi: rows only 8B-aligned (1170*4B) -> f32x2 nontemporal stores
        if (j + 2 <= GI_DIM) {
            f32x2 p01; p01.x = v[i][0]; p01.y = v[i][1];
            __builtin_nontemporal_store(p01, (f32x2*)(grow + j));
        }
        if (j + 4 <= GI_DIM) {
            f32x2 p23; p23.x = v[i][2]; p23.y = v[i][3];
            __builtin_nontemporal_store(p23, (f32x2*)(grow + j + 2));
        }
    }
}

// ---------------------------------------------------------------------------
// Clean bf16 GEMM + fused MLP layers 2/3: A16 [N_S][1216] bf16, branch-free
// batched staging with next-tile register prefetch (T14).
// ---------------------------------------------------------------------------
__global__ __launch_bounds__(256) void mention_gemm(
    const unsigned short* __restrict__ A16,
    const unsigned short* __restrict__ w1t, const float* __restrict__ b1,
    const unsigned short* __restrict__ w2t, const float* __restrict__ b2,
    const unsigned short* __restrict__ w3, const float* __restrict__ b3,
    float* __restrict__ out)
{
    __shared__ __align__(16) char smem[43008];
    const int SB_OFF = 16384;

    const int tid = threadIdx.x;
    const int w = tid >> 6;
    const int l = tid & 63;
    const int l15 = l & 15;
    const int lg = l >> 4;
    const int row0 = blockIdx.x * 128;

    f32x4 acc[2][10];
#pragma unroll
    for (int rf = 0; rf < 2; ++rf)
#pragma unroll
        for (int nf = 0; nf < 10; ++nf) acc[rf][nf] = (f32x4){0.f, 0.f, 0.f, 0.f};

    const int arow_base = w * 32 + l15;
    const int asw = (arow_base & 7) << 4;

    // batched staging registers (issue all loads back-to-back)
    s16x8 va[4], vb[5];
    {
        const int k0 = 0;
#pragma unroll
        for (int i = 0; i < 4; ++i) {
            int j = i * 256 + tid; int row = j >> 3, sub = j & 7;
            va[i] = *(const s16x8*)(A16 + (size_t)(row0 + row) * KP16 + k0 + sub * 8);
        }
#pragma unroll
        for (int i = 0; i < 5; ++i) {
            int idx = i * 256 + tid; int n = idx >> 3, s2 = idx & 7;
            vb[i] = *(const s16x8*)(w1t + (size_t)n * KP16 + k0 + s2 * 8);
        }
    }

    for (int t = 0; t < 19; ++t) {
        __syncthreads();   // all waves done reading previous LDS tile

        // ds_write staged registers (swizzled)
#pragma unroll
        for (int i = 0; i < 4; ++i) {
            int j = i * 256 + tid; int row = j >> 3, sub = j & 7;
            *(s16x8*)(smem + row * 128 + ((sub * 16) ^ ((row & 7) << 4))) = va[i];
        }
#pragma unroll
        for (int i = 0; i < 5; ++i) {
            int idx = i * 256 + tid; int n = idx >> 3, s2 = idx & 7;
            *(s16x8*)(smem + SB_OFF + n * 128 + ((s2 * 16) ^ ((n & 7) << 4))) = vb[i];
        }
        __syncthreads();

        // prefetch next tile (lands during MFMA phase)
        if (t + 1 < 19) {
            const int k0 = (t + 1) * 64;
#pragma unroll
            for (int i = 0; i < 4; ++i) {
                int j = i * 256 + tid; int row = j >> 3, sub = j & 7;
                va[i] = *(const s16x8*)(A16 + (size_t)(row0 + row) * KP16 + k0 + sub * 8);
            }
#pragma unroll
            for (int i = 0; i < 5; ++i) {
                int idx = i * 256 + tid; int n = idx >> 3, s2 = idx & 7;
                vb[i] = *(const s16x8*)(w1t + (size_t)n * KP16 + k0 + s2 * 8);
            }
        }

        // MFMA phase
#pragma unroll
        for (int kc = 0; kc < 2; ++kc) {
            const int inrowA = kc * 64 + lg * 16;
            s16x8 a0 = *(const s16x8*)(smem + arow_base * 128 + (inrowA ^ asw));
            s16x8 a1 = *(const s16x8*)(smem + arow_base * 128 + 2048 + (inrowA ^ asw));
#pragma unroll
            for (int nf = 0; nf < 10; ++nf) {
                const int n = nf * 16 + l15;
                s16x8 b = *(const s16x8*)(smem + SB_OFF + n * 128 + (inrowA ^ ((n & 7) << 4)));
                acc[0][nf] = __builtin_amdgcn_mfma_f32_16x16x32_bf16(a0, b, acc[0][nf], 0, 0, 0);
                acc[1][nf] = __builtin_amdgcn_mfma_f32_16x16x32_bf16(a1, b, acc[1][nf], 0, 0, 0);
            }
        }
    }

    __syncthreads();  // done with sA/sB, reuse as h1 buffer

    // ---- h1 = relu(acc + b1) -> LDS bf16 [128][336B] ----
    {
        float b1c[10];
#pragma unroll
        for (int nf = 0; nf < 10; ++nf) {
            int col = nf * 16 + l15;
            b1c[nf] = (col < HDIM) ? b1[col] : 0.f;
        }
#pragma unroll
        for (int rf = 0; rf < 2; ++rf)
#pragma unroll
            for (int nf = 0; nf < 10; ++nf)
#pragma unroll
                for (int r = 0; r < 4; ++r) {
                    int row = w * 32 + rf * 16 + lg * 4 + r;
                    int col = nf * 16 + l15;
                    float h = fmaxf(acc[rf][nf][r] + b1c[nf], 0.f);
                    *(unsigned short*)(smem + row * 336 + col * 2) = f2bf(h);
                }
    }
    __syncthreads();

    // ---- layer 2 ----
    f32x4 acc2[2][10];
#pragma unroll
    for (int rf = 0; rf < 2; ++rf)
#pragma unroll
        for (int nf = 0; nf < 10; ++nf) acc2[rf][nf] = (f32x4){0.f, 0.f, 0.f, 0.f};

#pragma unroll
    for (int kc = 0; kc < 5; ++kc) {
        s16x8 a0 = *(const s16x8*)(smem + (w * 32 + l15) * 336 + kc * 64 + lg * 16);
        s16x8 a1 = *(const s16x8*)(smem + (w * 32 + 16 + l15) * 336 + kc * 64 + lg * 16);
#pragma unroll
        for (int nf = 0; nf < 10; ++nf) {
            const int n = nf * 16 + l15;
            s16x8 b = *(const s16x8*)(w2t + n * 160 + kc * 32 + lg * 8);
            acc2[0][nf] = __builtin_amdgcn_mfma_f32_16x16x32_bf16(a0, b, acc2[0][nf], 0, 0, 0);
            acc2[1][nf] = __builtin_amdgcn_mfma_f32_16x16x32_bf16(a1, b, acc2[1][nf], 0, 0, 0);
        }
    }

    // ---- layer 3 ----
    {
        float b2c[10], w3c[10];
#pragma unroll
        for (int nf = 0; nf < 10; ++nf) {
            int col = nf * 16 + l15;
            b2c[nf] = (col < HDIM) ? b2[col] : 0.f;
            w3c[nf] = bf2f(w3[col]);
        }
#pragma unroll
        for (int rf = 0; rf < 2; ++rf)
#pragma unroll
            for (int r = 0; r < 4; ++r) {
                float ps = 0.f;
#pragma unroll
                for (int nf = 0; nf < 10; ++nf)
                    ps += fmaxf(acc2[rf][nf][r] + b2c[nf], 0.f) * w3c[nf];
                ps += __shfl_xor(ps, 1);
                ps += __shfl_xor(ps, 2);
                ps += __shfl_xor(ps, 4);
                ps += __shfl_xor(ps, 8);
                if (l15 == 0)
                    out[row0 + w * 32 + rf * 16 + lg * 4 + r] = ps + b3[0];
            }
    }
}

// ---------------------------------------------------------------------------
// Fallback / alfa MLP (proven round-2 kernel): A [M][K] f32 -> out [M]
// ---------------------------------------------------------------------------
template <int K, int NT>
__global__ __launch_bounds__(256) void mlp_mfma(
    const float* __restrict__ A,
    const unsigned short* __restrict__ w1t, const float* __restrict__ b1,
    const unsigned short* __restrict__ w2t, const float* __restrict__ b2,
    const unsigned short* __restrict__ w3, const float* __restrict__ b3,
    float* __restrict__ out)
{
    constexpr int KP = NT * 64;
    __shared__ __align__(16) char smem[43008];
    const int SB_OFF = 16384;

    const int tid = threadIdx.x;
    const int w = tid >> 6;
    const int l = tid & 63;
    const int l15 = l & 15;
    const int lg = l >> 4;
    const int row0 = blockIdx.x * 128;

    const int arow = tid >> 1;
    const int acb = (tid & 1) * 32;

    f32x4 acc[2][10];
#pragma unroll
    for (int rf = 0; rf < 2; ++rf)
#pragma unroll
        for (int nf = 0; nf < 10; ++nf) acc[rf][nf] = (f32x4){0.f, 0.f, 0.f, 0.f};

    const int arow_base = w * 32 + l15;
    const int asw = (arow_base & 7) << 4;

    for (int t = 0; t < NT; ++t) {
        const int k0 = t * 64;
        __syncthreads();

        unsigned short tmp[32];
        if (k0 + 64 <= K) {
            const float* src = A + (size_t)(row0 + arow) * K + k0 + acb;
#pragma unroll
            for (int i = 0; i < 16; ++i) {
                float2 v = ((const float2*)src)[i];
                tmp[2 * i] = f2bf(v.x);
                tmp[2 * i + 1] = f2bf(v.y);
            }
        } else {
            const float* arp = A + (size_t)(row0 + arow) * K;
#pragma unroll
            for (int i = 0; i < 32; ++i) {
                int col = k0 + acb + i;
                tmp[i] = (col < K) ? f2bf(arp[col]) : (unsigned short)0;
            }
        }
        {
            const int sw = (arow & 7) << 4;
#pragma unroll
            for (int i = 0; i < 4; ++i) {
                s16x8 pv;
#pragma unroll
                for (int j = 0; j < 8; ++j) pv[j] = (short)tmp[i * 8 + j];
                int inrow = acb * 2 + i * 16;
                *(s16x8*)(smem + arow * 128 + (inrow ^ sw)) = pv;
            }
        }

#pragma unroll
        for (int i = 0; i < 5; ++i) {
            int idx = i * 256 + tid;
            int n = idx >> 3, s2 = idx & 7;
            s16x8 v = *(const s16x8*)(w1t + (size_t)n * KP + k0 + s2 * 8);
            int inrow = s2 * 16;
            *(s16x8*)(smem + SB_OFF + n * 128 + (inrow ^ ((n & 7) << 4))) = v;
        }

        __syncthreads();

#pragma unroll
        for (int kc = 0; kc < 2; ++kc) {
            const int inrowA = kc * 64 + lg * 16;
            s16x8 a0 = *(const s16x8*)(smem + arow_base * 128 + (inrowA ^ asw));
            s16x8 a1 = *(const s16x8*)(smem + arow_base * 128 + 2048 + (inrowA ^ asw));
#pragma unroll
            for (int nf = 0; nf < 10; ++nf) {
                const int n = nf * 16 + l15;
                s16x8 b = *(const s16x8*)(smem + SB_OFF + n * 128 + (inrowA ^ ((n & 7) << 4)));
                acc[0][nf] = __builtin_amdgcn_mfma_f32_16x16x32_bf16(a0, b, acc[0][nf], 0, 0, 0);
                acc[1][nf] = __builtin_amdgcn_mfma_f32_16x16x32_bf16(a1, b, acc[1][nf], 0, 0, 0);
            }
        }
    }

    __syncthreads();

    {
        float b1c[10];
#pragma unroll
        for (int nf = 0; nf < 10; ++nf) {
            int col = nf * 16 + l15;
            b1c[nf] = (col < HDIM) ? b1[col] : 0.f;
        }
#pragma unroll
        for (int rf = 0; rf < 2; ++rf)
#pragma unroll
            for (int nf = 0; nf < 10; ++nf)
#pragma unroll
                for (int r = 0; r < 4; ++r) {
                    int row = w * 32 + rf * 16 + lg * 4 + r;
                    int col = nf * 16 + l15;
                    float h = fmaxf(acc[rf][nf][r] + b1c[nf], 0.f);
                    *(unsigned short*)(smem + row * 336 + col * 2) = f2bf(h);
                }
    }
    __syncthreads();

    f32x4 acc2[2][10];
#pragma unroll
    for (int rf = 0; rf < 2; ++rf)
#pragma unroll
        for (int nf = 0; nf < 10; ++nf) acc2[rf][nf] = (f32x4){0.f, 0.f, 0.f, 0.f};

#pragma unroll
    for (int kc = 0; kc < 5; ++kc) {
        s16x8 a0 = *(const s16x8*)(smem + (w * 32 + l15) * 336 + kc * 64 + lg * 16);
        s16x8 a1 = *(const s16x8*)(smem + (w * 32 + 16 + l15) * 336 + kc * 64 + lg * 16);
#pragma unroll
        for (int nf = 0; nf < 10; ++nf) {
            const int n = nf * 16 + l15;
            s16x8 b = *(const s16x8*)(w2t + n * 160 + kc * 32 + lg * 8);
            acc2[0][nf] = __builtin_amdgcn_mfma_f32_16x16x32_bf16(a0, b, acc2[0][nf], 0, 0, 0);
            acc2[1][nf] = __builtin_amdgcn_mfma_f32_16x16x32_bf16(a1, b, acc2[1][nf], 0, 0, 0);
        }
    }

    {
        float b2c[10], w3c[10];
#pragma unroll
        for (int nf = 0; nf < 10; ++nf) {
            int col = nf * 16 + l15;
            b2c[nf] = (col < HDIM) ? b2[col] : 0.f;
            w3c[nf] = bf2f(w3[col]);
        }
#pragma unroll
        for (int rf = 0; rf < 2; ++rf)
#pragma unroll
            for (int r = 0; r < 4; ++r) {
                float ps = 0.f;
#pragma unroll
                for (int nf = 0; nf < 10; ++nf)
                    ps += fmaxf(acc2[rf][nf][r] + b2c[nf], 0.f) * w3c[nf];
                ps += __shfl_xor(ps, 1);
                ps += __shfl_xor(ps, 2);
                ps += __shfl_xor(ps, 4);
                ps += __shfl_xor(ps, 8);
                if (l15 == 0)
                    out[row0 + w * 32 + rf * 16 + lg * 4 + r] = ps + b3[0];
            }
    }
}

extern "C" void kernel_launch(void* const* d_in, const int* in_sizes, int n_in,
                              void* d_out, int out_size, void* d_ws, size_t ws_size,
                              hipStream_t stream)
{
    const float* states = (const float*)d_in[0];
    const float* embeds = (const float*)d_in[1];
    const int*   starts = (const int*)d_in[2];
    const int*   widths = (const int*)d_in[3];
    const float* aW1 = (const float*)d_in[4];
    const float* ab1 = (const float*)d_in[5];
    const float* aW2 = (const float*)d_in[6];
    const float* ab2 = (const float*)d_in[7];
    const float* aW3 = (const float*)d_in[8];
    const float* ab3 = (const float*)d_in[9];
    const float* wtab = (const float*)d_in[10];
    const float* sW1 = (const float*)d_in[11];
    const float* sb1 = (const float*)d_in[12];
    const float* sW2 = (const float*)d_in[13];
    const float* sb2 = (const float*)d_in[14];
    const float* sW3 = (const float*)d_in[15];
    const float* sb3 = (const float*)d_in[16];

    float* gi = (float*)d_out;
    float* scores = gi + (size_t)N_S * GI_DIM;

    char* ws = (char*)d_ws;
    float* alfa = (float*)ws;                                   // 320000 B
    unsigned short* w1t_m = (unsigned short*)(ws + 320512);     // 389120
    unsigned short* w2t_m = (unsigned short*)(ws + 709632);     // 51200
    unsigned short* w3_m  = (unsigned short*)(ws + 760832);     // 320
    unsigned short* w1t_a = (unsigned short*)(ws + 761344);     // 143360
    unsigned short* w2t_a = (unsigned short*)(ws + 904704);     // 51200
    unsigned short* w3_a  = (unsigned short*)(ws + 955904);     // 320
    const size_t GI16_OFF = 956416;
    const size_t GI16_BYTES = (size_t)N_S * KP16 * 2;           // 389.12 MB
    unsigned short* gi16 = (unsigned short*)(ws + GI16_OFF);
    const bool have_ws = (ws_size >= GI16_OFF + GI16_BYTES);

    // 0) convert/transpose/pad weights to bf16
    convert_kernel<<<1242, 256, 0, stream>>>(sW1, sW2, sW3, aW1, aW2, aW3,
                                             w1t_m, w2t_m, w3_m, w1t_a, w2t_a, w3_a);

    // 1) alfa = attention-MLP(states)
    mlp_mfma<D_STATE, 7><<<N_T / 128, 256, 0, stream>>>(
        states, w1t_a, ab1, w2t_a, ab2, w3_a, ab3, alfa);

    if (have_ws) {
        // 2) g_i build: f32 output + bf16 shadow (batched loads, nt stores)
        gi_build<1><<<N_S / 4, 256, 0, stream>>>(
            states, embeds, starts, widths, alfa, wtab, gi, gi16);
        // 3) clean bf16 GEMM + MLP layers 2/3
        mention_gemm<<<N_S / 128, 256, 0, stream>>>(
            gi16, w1t_m, sb1, w2t_m, sb2, w3_m, sb3, scores);
    } else {
        // fallback: f32 g_i only, proven round-2 GEMM from f32
        gi_build<0><<<N_S / 4, 256, 0, stream>>>(
            states, embeds, starts, widths, alfa, wtab, gi, (unsigned short*)0);
        mlp_mfma<GI_DIM, 19><<<N_S / 128, 256, 0, stream>>>(
            gi, w1t_m, sb1, w2t_m, sb2, w3_m, sb3, scores);
    }
}